// Round 10
// baseline (1879.529 us; speedup 1.0000x reference)
//
#include <hip/hip_runtime.h>
#include <cstdint>
#include <cstddef>

// ---------------------------------------------------------------------------
// AdaptiveLSTMBlockWrapper — round 10: 2 blocks/CU (4 waves/SIMD).
// Tile 128x256, grid 512, LDS 64KB/block (2 x 32KB A-only buffers, proven
// zero-conflict geometry: 128B rows, 8x16B slots, slot^(row&7)).
// B global->reg from L2-resident slab, loaded per-2-nf (low VGPR).
// launch_bounds(512,4) caps VGPR at 128 so two blocks co-reside per CU;
// independent block barriers overlap each other's MFMA clusters.
// fp32 GEMM = 3-product split-f16 MFMA (Ah*Bh + Ah*Bl + Al*Bh).
// ---------------------------------------------------------------------------

typedef _Float16 f16;
typedef f16   f16x8 __attribute__((ext_vector_type(8)));
typedef f16   f16x4 __attribute__((ext_vector_type(4)));
typedef float f32x4 __attribute__((ext_vector_type(4)));

#define TSTEPS 12

// d_out float offsets
#define O_ACC   0u
#define O_H1    4194304u
#define O_C1    8388608u
#define O_H2    12582912u
#define O_C2    16777216u
#define O_PCOST 20971520u
#define O_PSTEP 20971521u

// ws byte offsets
#define WS_C1    ((size_t)0u)
#define WS_C2    ((size_t)16u<<20)
#define WS_H1HI  ((size_t)32u<<20)
#define WS_H1LO  ((size_t)40u<<20)
#define WS_H2HI  ((size_t)48u<<20)
#define WS_H2LO  ((size_t)56u<<20)
#define WS_ACTHI ((size_t)64u<<20)
#define WS_ACTLO ((size_t)72u<<20)
#define WS_W2HI  ((size_t)80u<<20)
#define WS_W2LO  ((size_t)88u<<20)
#define WS_W3HI  ((size_t)96u<<20)
#define WS_W3LO  ((size_t)104u<<20)
#define WS_MISC  ((size_t)112u<<20)

// LDS: 2 buffers; within a buffer: Ahi at 0 (16KB), Alo at 16384 (16KB)
#define SEC_ALO 16384
#define BUFSZ   32768

__device__ __forceinline__ float sigmoidf_(float x) { return 1.0f / (1.0f + expf(-x)); }

__device__ __forceinline__ void glds16(const void* g, void* l) {
    __builtin_amdgcn_global_load_lds(
        (const __attribute__((address_space(1))) unsigned int*)g,
        (__attribute__((address_space(3))) unsigned int*)l, 16, 0, 0);
}

// Grid: 512 blocks (32 m x 16 hc). XCD-major over hc: 2MB weight slab/XCD.
__device__ __forceinline__ void block_tile(int& m0, int& hc0) {
    const int bid = blockIdx.x;
    const int lid = (bid & 7) * 64 + (bid >> 3);
    m0  = (lid & 31) * 128;
    hc0 = (lid >> 5) * 64;
}

// ---------------------------------------------------------------------------
// acc += A(128 rows x 1024) * B(256 vcols x 1024)^T, split-f16 3-product.
// A: pre-split f16 pairs, glds into LDS (128B rows, 8x16B slots, invariant:
//    slot s of row r holds k-chunk s^(r&7)) — proven zero-conflict.
// B: straight to registers, 2 nf at a time (16 VGPR live). B_PAIR: direct
//    f16x8 loads; else fp32 + split on the fly (stepA only).
// Wave wid: rows wm=(wid>>2)*64 (mf 0..3), vcols nf=0..3 at
//    wrow = nf*1024 + hc0 + (wid&3)*16 + l15; lane k-chunk lk*8.
// Per kt: issueA(kt+1); {ks,np}: load B(2nf) -> {mg}: 4 A-frag reads + 12
// MFMA; vmcnt(0)+barrier. Latency hiding via 4 waves/SIMD (2 blocks/CU).
// ---------------------------------------------------------------------------
template<bool B_PAIR>
__device__ __forceinline__ void passK64(
    const f16* __restrict__ Ahi, const f16* __restrict__ Alo,
    const f16* __restrict__ Bhi, const f16* __restrict__ Blo,
    const float* __restrict__ Bf32,
    int m0, int hc0, f32x4 (&acc)[4][4], char* sm)
{
    const int tid = threadIdx.x, lane = tid & 63, wid = tid >> 6;
    const int wm  = (wid >> 2) * 64;
    const int wnb = wid & 3;
    const int l15 = lane & 15, lk = lane >> 4;

    // A fragment read offsets (per mf)
    int rbase[4], rx[4];
#pragma unroll
    for (int mf = 0; mf < 4; ++mf) {
        const int row = wm + mf * 16 + l15;
        rbase[mf] = row * 128;
        rx[mf]    = row & 7;
    }

    // A glds: 4 ops/wave. o = wid*4+i: sec = wid>>2, j = (wid&3)*4 + i.
    // lane l: row-in-chunk = l>>3, slot = l&7, global k-chunk = (l&7)^(l>>3).
    const int secA = wid >> 2;
    const int j0   = (wid & 3) * 4;
    const int rl = lane >> 3, sl = lane & 7;
    const f16* gaBase = (secA ? Alo : Ahi)
                        + (size_t)(m0 + j0 * 8 + rl) * 1024 + ((sl ^ rl) << 3);
    const int lb0 = secA * SEC_ALO + j0 * 1024;

    // B base pointers
    const int wrow0 = hc0 + wnb * 16 + l15;
    const float* pB32 = nullptr;
    const f16* pBh = nullptr;
    const f16* pBl = nullptr;
    if constexpr (B_PAIR) {
        pBh = Bhi + (size_t)wrow0 * 1024 + lk * 8;
        pBl = Blo + (size_t)wrow0 * 1024 + lk * 8;
    } else {
        pB32 = Bf32 + (size_t)wrow0 * 1024 + lk * 8;
    }

    auto issueA = [&](int kt, char* buf) {
#pragma unroll
        for (int i = 0; i < 4; ++i)
            glds16(gaBase + (size_t)i * 8192 + kt * 64, buf + lb0 + i * 1024);
    };

    // ---- prologue ----
    issueA(0, sm);
    asm volatile("s_waitcnt vmcnt(0)" ::: "memory");
    __builtin_amdgcn_s_barrier();
    asm volatile("" ::: "memory");

#pragma unroll 1
    for (int kt = 0; kt < 16; ++kt) {
        char* bc = sm + (kt & 1) * BUFSZ;
        char* bn = sm + ((kt + 1) & 1) * BUFSZ;
        if (kt < 15) issueA(kt + 1, bn);

#pragma unroll
        for (int ks = 0; ks < 2; ++ks) {
#pragma unroll
            for (int np = 0; np < 2; ++np) {
                // load B fragments for nf = 2np, 2np+1
                f16x8 bh[2], bl[2];
#pragma unroll
                for (int q = 0; q < 2; ++q) {
                    const size_t bo = (size_t)(2 * np + q) * 1048576 + kt * 64 + ks * 32;
                    if constexpr (B_PAIR) {
                        bh[q] = *(const f16x8*)(pBh + bo);
                        bl[q] = *(const f16x8*)(pBl + bo);
                    } else {
                        const float* p = pB32 + bo;
                        const float4 v0 = *(const float4*)(p);
                        const float4 v1 = *(const float4*)(p + 4);
                        const float f[8] = {v0.x, v0.y, v0.z, v0.w, v1.x, v1.y, v1.z, v1.w};
                        f16x8 h, l;
#pragma unroll
                        for (int j = 0; j < 8; ++j) {
                            const f16 a = (f16)f[j];
                            h[j] = a; l[j] = (f16)(f[j] - (float)a);
                        }
                        bh[q] = h; bl[q] = l;
                    }
                }
#pragma unroll
                for (int mg = 0; mg < 2; ++mg) {
                    const int o0 = rbase[2 * mg]     + ((((ks << 2) | lk) ^ rx[2 * mg])     << 4);
                    const int o1 = rbase[2 * mg + 1] + ((((ks << 2) | lk) ^ rx[2 * mg + 1]) << 4);
                    const f16x8 ah0 = *(const f16x8*)(bc + o0);
                    const f16x8 al0 = *(const f16x8*)(bc + SEC_ALO + o0);
                    const f16x8 ah1 = *(const f16x8*)(bc + o1);
                    const f16x8 al1 = *(const f16x8*)(bc + SEC_ALO + o1);
                    __builtin_amdgcn_s_setprio(1);
#pragma unroll
                    for (int q = 0; q < 2; ++q) {
                        acc[2 * mg][2 * np + q]     = __builtin_amdgcn_mfma_f32_16x16x32_f16(ah0, bh[q], acc[2 * mg][2 * np + q], 0, 0, 0);
                        acc[2 * mg + 1][2 * np + q] = __builtin_amdgcn_mfma_f32_16x16x32_f16(ah1, bh[q], acc[2 * mg + 1][2 * np + q], 0, 0, 0);
                    }
#pragma unroll
                    for (int q = 0; q < 2; ++q) {
                        acc[2 * mg][2 * np + q]     = __builtin_amdgcn_mfma_f32_16x16x32_f16(ah0, bl[q], acc[2 * mg][2 * np + q], 0, 0, 0);
                        acc[2 * mg + 1][2 * np + q] = __builtin_amdgcn_mfma_f32_16x16x32_f16(ah1, bl[q], acc[2 * mg + 1][2 * np + q], 0, 0, 0);
                    }
#pragma unroll
                    for (int q = 0; q < 2; ++q) {
                        acc[2 * mg][2 * np + q]     = __builtin_amdgcn_mfma_f32_16x16x32_f16(al0, bh[q], acc[2 * mg][2 * np + q], 0, 0, 0);
                        acc[2 * mg + 1][2 * np + q] = __builtin_amdgcn_mfma_f32_16x16x32_f16(al1, bh[q], acc[2 * mg + 1][2 * np + q], 0, 0, 0);
                    }
                    __builtin_amdgcn_s_setprio(0);
                }
            }
        }
        asm volatile("s_waitcnt vmcnt(0)" ::: "memory");  // glds ~1 kt old
        if (kt < 15) {
            __builtin_amdgcn_s_barrier();
            asm volatile("" ::: "memory");
        }
    }
}

// Z1 = x@W1^T + b_ih1 + b_hh1 (x pairs staged; W1 pairs direct-to-reg)
__global__ __launch_bounds__(512, 4) void k_z1(
    const f16* __restrict__ xhi, const f16* __restrict__ xlo,
    const f16* __restrict__ W1hi, const f16* __restrict__ W1lo,
    const float* __restrict__ bih1, const float* __restrict__ bhh1,
    float* __restrict__ Z1)
{
    __shared__ __align__(16) char sm[2 * BUFSZ];
    int m0, hc0; block_tile(m0, hc0);
    f32x4 acc[4][4];
#pragma unroll
    for (int a = 0; a < 4; ++a)
#pragma unroll
        for (int b = 0; b < 4; ++b) acc[a][b] = (f32x4){0.f, 0.f, 0.f, 0.f};
    passK64<true>(xhi, xlo, W1hi, W1lo, nullptr, m0, hc0, acc, sm);

    const int tid = threadIdx.x, lane = tid & 63, wid = tid >> 6;
    const int wm = (wid >> 2) * 64, wnb = wid & 3, l15 = lane & 15, lk = lane >> 4;
    const int hc = hc0 + wnb * 16 + l15;
#pragma unroll
    for (int mf = 0; mf < 4; ++mf)
#pragma unroll
        for (int r = 0; r < 4; ++r) {
            const int row = m0 + wm + mf * 16 + lk * 4 + r;
#pragma unroll
            for (int g = 0; g < 4; ++g) {
                const int R = g * 1024 + hc;
                Z1[(size_t)row * 4096 + R] = acc[mf][g][r] + bih1[R] + bhh1[R];
            }
        }
}

// Layer-1 cell: gates = Z1 (+flag col @step0) + h1@Whh1^T   (in-place h1/act)
__global__ __launch_bounds__(512, 4) void k_stepA(
    const float* __restrict__ Z1, const float* __restrict__ Whh1,
    const float* __restrict__ flagcol, float* __restrict__ c1,
    f16* __restrict__ h1hi, f16* __restrict__ h1lo,
    f16* __restrict__ acthi, f16* __restrict__ actlo,
    const unsigned* __restrict__ cnt_prev, int step)
{
    if (step > 0 && cnt_prev[0] == 0u) return;
    __shared__ __align__(16) char sm[2 * BUFSZ];
    int m0, hc0; block_tile(m0, hc0);
    f32x4 acc[4][4];
#pragma unroll
    for (int a = 0; a < 4; ++a)
#pragma unroll
        for (int b = 0; b < 4; ++b) acc[a][b] = (f32x4){0.f, 0.f, 0.f, 0.f};
    if (step > 0)
        passK64<false>(h1hi, h1lo, nullptr, nullptr, Whh1, m0, hc0, acc, sm);

    const int tid = threadIdx.x, lane = tid & 63, wid = tid >> 6;
    const int wm = (wid >> 2) * 64, wnb = wid & 3, l15 = lane & 15, lk = lane >> 4;
    const int hc = hc0 + wnb * 16 + l15;
#pragma unroll
    for (int mf = 0; mf < 4; ++mf)
#pragma unroll
        for (int r = 0; r < 4; ++r) {
            const int row = m0 + wm + mf * 16 + lk * 4 + r;
            float p[4];
#pragma unroll
            for (int g = 0; g < 4; ++g) {
                const int R = g * 1024 + hc;
                p[g] = acc[mf][g][r] + Z1[(size_t)row * 4096 + R];
                if (step == 0) p[g] += flagcol[R];
            }
            const float ig = sigmoidf_(p[0]);
            const float fg = sigmoidf_(p[1]);
            const float gg = tanhf(p[2]);
            const float og = sigmoidf_(p[3]);
            const int idx = row * 1024 + hc;
            const float cold = (step == 0) ? 0.0f : c1[idx];
            const float cn = fg * cold + ig * gg;
            c1[idx] = cn;
            const float h = og * tanhf(cn);
            const f16 hh = (f16)h;
            const f16 hl = (f16)(h - (float)hh);
            h1hi[idx] = hh; h1lo[idx] = hl;
            const bool pos = h > 0.0f;
            acthi[idx] = pos ? hh : (f16)0.0f;
            actlo[idx] = pos ? hl : (f16)0.0f;
        }
}

// Layer-2 cell: gates = b2 + act@Wih2^T + h2@Whh2^T   (in-place h2; B pairs)
__global__ __launch_bounds__(512, 4) void k_stepB(
    const f16* __restrict__ acthi, const f16* __restrict__ actlo,
    const f16* __restrict__ W2hi, const f16* __restrict__ W2lo,
    f16* __restrict__ h2hi, f16* __restrict__ h2lo,
    const f16* __restrict__ W3hi, const f16* __restrict__ W3lo,
    const float* __restrict__ bih2, const float* __restrict__ bhh2,
    float* __restrict__ c2,
    const unsigned* __restrict__ cnt_prev, int step)
{
    if (step > 0 && cnt_prev[0] == 0u) return;
    __shared__ __align__(16) char sm[2 * BUFSZ];
    int m0, hc0; block_tile(m0, hc0);
    f32x4 acc[4][4];
#pragma unroll
    for (int a = 0; a < 4; ++a)
#pragma unroll
        for (int b = 0; b < 4; ++b) acc[a][b] = (f32x4){0.f, 0.f, 0.f, 0.f};
    passK64<true>(acthi, actlo, W2hi, W2lo, nullptr, m0, hc0, acc, sm);
    if (step > 0)
        passK64<true>(h2hi, h2lo, W3hi, W3lo, nullptr, m0, hc0, acc, sm);

    const int tid = threadIdx.x, lane = tid & 63, wid = tid >> 6;
    const int wm = (wid >> 2) * 64, wnb = wid & 3, l15 = lane & 15, lk = lane >> 4;
    const int hc = hc0 + wnb * 16 + l15;
#pragma unroll
    for (int mf = 0; mf < 4; ++mf)
#pragma unroll
        for (int r = 0; r < 4; ++r) {
            const int row = m0 + wm + mf * 16 + lk * 4 + r;
            float p[4];
#pragma unroll
            for (int g = 0; g < 4; ++g) {
                const int R = g * 1024 + hc;
                p[g] = acc[mf][g][r] + bih2[R] + bhh2[R];
            }
            const float ig = sigmoidf_(p[0]);
            const float fg = sigmoidf_(p[1]);
            const float gg = tanhf(p[2]);
            const float og = sigmoidf_(p[3]);
            const int idx = row * 1024 + hc;
            const float cold = (step == 0) ? 0.0f : c2[idx];
            const float cn = fg * cold + ig * gg;
            c2[idx] = cn;
            const float h = og * tanhf(cn);
            const f16 hh = (f16)h;
            h2hi[idx] = hh;
            h2lo[idx] = (f16)(h - (float)hh);
        }
}

// Merged halting state machine + acc_out accumulate (one wave per row).
__global__ __launch_bounds__(256) void k_haltacc(
    const f16* __restrict__ h2hi, const f16* __restrict__ h2lo,
    const float* __restrict__ Whalt, const float* __restrict__ bhalt,
    float* __restrict__ halt, float* __restrict__ cont,
    float* __restrict__ ponder_out, unsigned* __restrict__ ctrl,
    float* __restrict__ acc_out,
    const unsigned* __restrict__ cnt_prev, int step)
{
    if (step > 0 && cnt_prev[0] == 0u) return;
    const int lane = threadIdx.x & 63;
    const int b = blockIdx.x * 4 + (threadIdx.x >> 6);
    const size_t base = (size_t)b * 1024;
    float sum = 0.0f;
    for (int k = lane; k < 1024; k += 64)
        sum += ((float)h2hi[base + k] + (float)h2lo[base + k]) * Whalt[k];
#pragma unroll
    for (int off = 32; off > 0; off >>= 1) sum += __shfl_down(sum, off, 64);
    float co = 0.0f;
    if (lane == 0) {
        const float sh = sigmoidf_(sum + bhalt[0]);
        if (cont[b] != 0.0f) {
            const float hn = halt[b] + sh;
            const bool ending = hn > 0.99f;
            co = sh + (ending ? (1.0f - hn) : 0.0f);
            halt[b] = hn;
            if (!ending) {
                ponder_out[b] += 1.0f;
                atomicAdd(&ctrl[step], 1u);
            } else {
                cont[b] = 0.0f;
            }
        }
    }
    co = __shfl(co, 0, 64);
    if (step == 0 || co != 0.0f) {
        float4* dst = (float4*)(acc_out + base);
        const f16x4* hi4 = (const f16x4*)(h2hi + base);
        const f16x4* lo4 = (const f16x4*)(h2lo + base);
#pragma unroll
        for (int j = 0; j < 4; ++j) {
            const int i = lane + 64 * j;
            const f16x4 hv = hi4[i];
            const f16x4 lv = lo4[i];
            float4 d = (step == 0) ? (float4){0.f, 0.f, 0.f, 0.f} : dst[i];
            d.x = fmaf(co, (float)hv[0] + (float)lv[0], d.x);
            d.y = fmaf(co, (float)hv[1] + (float)lv[1], d.y);
            d.z = fmaf(co, (float)hv[2] + (float)lv[2], d.z);
            d.w = fmaf(co, (float)hv[3] + (float)lv[3], d.w);
            dst[i] = d;
        }
    }
}

__global__ __launch_bounds__(256) void k_small_init(
    float* __restrict__ halt, float* __restrict__ cont,
    float* __restrict__ ponder_out, unsigned* __restrict__ ctrl)
{
    const int b = blockIdx.x * 256 + threadIdx.x;
    if (b < 4096) { halt[b] = 0.0f; cont[b] = 1.0f; ponder_out[b] = 0.0f; }
    if (b < 16) ctrl[b] = 0u;
}

// flat fp32 -> f16 hi/lo pairs (4096*1024 elements)
__global__ __launch_bounds__(256) void k_split_flat(
    const float* __restrict__ src, f16* __restrict__ hi, f16* __restrict__ lo)
{
    const size_t i = ((size_t)blockIdx.x * 256 + threadIdx.x) * 4;
    const float4 v = *(const float4*)(src + i);
    const f16 s0 = (f16)v.x, s1 = (f16)v.y, s2 = (f16)v.z, s3 = (f16)v.w;
    const f16x4 hv = {s0, s1, s2, s3};
    const f16x4 lw = {(f16)(v.x - (float)s0), (f16)(v.y - (float)s1),
                      (f16)(v.z - (float)s2), (f16)(v.w - (float)s3)};
    *(f16x4*)(hi + i) = hv;
    *(f16x4*)(lo + i) = lw;
}

// Wih1 [4096][1025]: cols 0..1023 -> pairs; col 1024 -> flagcol
__global__ __launch_bounds__(256) void k_split_wih1(
    const float* __restrict__ src, f16* __restrict__ hi, f16* __restrict__ lo,
    float* __restrict__ flagcol)
{
    const int t = blockIdx.x * 256 + threadIdx.x;
    const int row = t >> 8, c4 = (t & 255) << 2;
    const float* s = src + (size_t)row * 1025 + c4;
    const float v0 = s[0], v1 = s[1], v2 = s[2], v3 = s[3];
    const f16 s0 = (f16)v0, s1 = (f16)v1, s2 = (f16)v2, s3 = (f16)v3;
    const f16x4 hv = {s0, s1, s2, s3};
    const f16x4 lw = {(f16)(v0 - (float)s0), (f16)(v1 - (float)s1),
                      (f16)(v2 - (float)s2), (f16)(v3 - (float)s3)};
    const size_t di = (size_t)row * 1024 + c4;
    *(f16x4*)(hi + di) = hv;
    *(f16x4*)(lo + di) = lw;
    if ((t & 255) == 0) flagcol[row] = src[(size_t)row * 1025 + 1024];
}

// finalize: states to d_out + remainder term
__global__ __launch_bounds__(256) void k_fin1(
    const f16* __restrict__ h1hi, const f16* __restrict__ h1lo,
    const f16* __restrict__ h2hi, const f16* __restrict__ h2lo,
    const float* __restrict__ c1s, const float* __restrict__ c2s,
    const float* __restrict__ halt, const float* __restrict__ cont,
    float* __restrict__ out)
{
    const int b = blockIdx.x;
    const float rem = (cont[b] != 0.0f) ? (1.0f - halt[b]) : 0.0f;
    const int base = b * 1024;
    for (int i = threadIdx.x; i < 1024; i += 256) {
        const float h1v = (float)h1hi[base + i] + (float)h1lo[base + i];
        const float h2v = (float)h2hi[base + i] + (float)h2lo[base + i];
        out[O_H1 + base + i] = h1v;
        out[O_C1 + base + i] = c1s[base + i];
        out[O_H2 + base + i] = h2v;
        out[O_C2 + base + i] = c2s[base + i];
        if (rem != 0.0f) out[O_ACC + base + i] += rem * h2v;
    }
}

__global__ __launch_bounds__(256) void k_fin2(
    const float* __restrict__ halt, float* __restrict__ out)
{
    __shared__ float red[256];
    float s = 0.0f;
    for (int i = threadIdx.x; i < 4096; i += 256) s += halt[i];
    red[threadIdx.x] = s;
    __syncthreads();
    for (int w = 128; w > 0; w >>= 1) {
        if (threadIdx.x < w) red[threadIdx.x] += red[threadIdx.x + w];
        __syncthreads();
    }
    if (threadIdx.x == 0) out[O_PCOST] = -0.01f * (red[0] * (1.0f / 4096.0f));
}

extern "C" void kernel_launch(void* const* d_in, const int* in_sizes, int n_in,
                              void* d_out, int out_size, void* d_ws, size_t ws_size,
                              hipStream_t stream) {
    const float* inputs = (const float*)d_in[0];
    const float* W_ih1  = (const float*)d_in[1];
    const float* W_hh1  = (const float*)d_in[2];
    const float* b_ih1  = (const float*)d_in[3];
    const float* b_hh1  = (const float*)d_in[4];
    const float* W_ih2  = (const float*)d_in[5];
    const float* W_hh2  = (const float*)d_in[6];
    const float* b_ih2  = (const float*)d_in[7];
    const float* b_hh2  = (const float*)d_in[8];
    const float* W_halt = (const float*)d_in[9];
    const float* b_halt = (const float*)d_in[10];

    float* out = (float*)d_out;
    float* Z1  = out + O_H1;                  // 64 MB in d_out's dead state region

    char* wsb = (char*)d_ws;
    float* c1s = (float*)(wsb + WS_C1);
    float* c2s = (float*)(wsb + WS_C2);
    f16* h1hi = (f16*)(wsb + WS_H1HI);
    f16* h1lo = (f16*)(wsb + WS_H1LO);
    f16* h2hi = (f16*)(wsb + WS_H2HI);
    f16* h2lo = (f16*)(wsb + WS_H2LO);
    f16* acthi = (f16*)(wsb + WS_ACTHI);
    f16* actlo = (f16*)(wsb + WS_ACTLO);
    f16* W2hi = (f16*)(wsb + WS_W2HI);
    f16* W2lo = (f16*)(wsb + WS_W2LO);
    f16* W3hi = (f16*)(wsb + WS_W3HI);
    f16* W3lo = (f16*)(wsb + WS_W3LO);
    float* halt    = (float*)(wsb + WS_MISC);
    float* cont    = halt + 4096;
    float* flagcol = cont + 4096;
    unsigned* ctrl = (unsigned*)(flagcol + 4096);

    // z1 temporaries in step-0-dead state slots: x pairs in h1, W1 pairs in h2
    f16* xhi  = h1hi; f16* xlo  = h1lo;
    f16* W1hi = h2hi; f16* W1lo = h2lo;

    k_small_init<<<16, 256, 0, stream>>>(halt, cont, out + O_PSTEP, ctrl);

    k_split_wih1<<<4096, 256, 0, stream>>>(W_ih1, W1hi, W1lo, flagcol);
    k_split_flat<<<4096, 256, 0, stream>>>(inputs, xhi, xlo);
    k_split_flat<<<4096, 256, 0, stream>>>(W_ih2, W2hi, W2lo);
    k_split_flat<<<4096, 256, 0, stream>>>(W_hh2, W3hi, W3lo);
    k_z1<<<512, 512, 0, stream>>>(xhi, xlo, W1hi, W1lo, b_ih1, b_hh1, Z1);

    for (int s = 0; s < TSTEPS; ++s) {
        const unsigned* cnt_prev = ctrl + (s > 0 ? s - 1 : 0);

        k_stepA<<<512, 512, 0, stream>>>(Z1, W_hh1, flagcol, c1s,
                                         h1hi, h1lo, acthi, actlo,
                                         cnt_prev, s);
        k_stepB<<<512, 512, 0, stream>>>(acthi, actlo, W2hi, W2lo,
                                         h2hi, h2lo, W3hi, W3lo,
                                         b_ih2, b_hh2, c2s,
                                         cnt_prev, s);
        k_haltacc<<<1024, 256, 0, stream>>>(h2hi, h2lo, W_halt, b_halt,
                                            halt, cont, out + O_PSTEP, ctrl,
                                            out + O_ACC, cnt_prev, s);
    }

    k_fin1<<<4096, 256, 0, stream>>>(h1hi, h1lo, h2hi, h2lo,
                                     c1s, c2s, halt, cont, out);
    k_fin2<<<1, 256, 0, stream>>>(halt, out);
}

// Round 11
// 1414.806 us; speedup vs baseline: 1.3285x; 1.3285x over previous
//
#include <hip/hip_runtime.h>
#include <cstdint>
#include <cstddef>

// ---------------------------------------------------------------------------
// AdaptiveLSTMBlockWrapper — round 11: R9 engine + FRAGMENT-PACKED weights.
// W1/W2/W3 f16 hi/lo pairs stored in MFMA-operand order so every B fragment
// load is ONE contiguous 1KB coalesced transaction (base + C*1024 + lane*16)
// instead of a 64-line gather (16B/lane at 2KB lane stride).
//   chunk C = T*512 + kt*32 + ks*16 + wnb*4 + nf   (T = hc0/64)
//   element (row = nf*1024 + T*64 + wnb*16 + (lane&15),
//            k   = kt*64 + ks*32 + (lane>>4)*8 .. +8)
// stepA keeps the r9 fp32-gather path unchanged (control experiment).
// Engine: 256x256 block, 8 waves (2Mx4N), BK=64, A-only LDS double buffer
// (proven 0-conflict: 128B rows, 8x16B slots, slot^(row&7)), 1 barrier/kt,
// product-major 3-product split-f16 MFMA, setprio around sweeps.
// ---------------------------------------------------------------------------

typedef _Float16 f16;
typedef f16   f16x8 __attribute__((ext_vector_type(8)));
typedef f16   f16x4 __attribute__((ext_vector_type(4)));
typedef float f32x4 __attribute__((ext_vector_type(4)));

#define TSTEPS 12

// d_out float offsets
#define O_ACC   0u
#define O_H1    4194304u
#define O_C1    8388608u
#define O_H2    12582912u
#define O_C2    16777216u
#define O_PCOST 20971520u
#define O_PSTEP 20971521u

// ws byte offsets
#define WS_C1    ((size_t)0u)
#define WS_C2    ((size_t)16u<<20)
#define WS_H1HI  ((size_t)32u<<20)
#define WS_H1LO  ((size_t)40u<<20)
#define WS_H2HI  ((size_t)48u<<20)
#define WS_H2LO  ((size_t)56u<<20)
#define WS_ACTHI ((size_t)64u<<20)
#define WS_ACTLO ((size_t)72u<<20)
#define WS_W2HI  ((size_t)80u<<20)
#define WS_W2LO  ((size_t)88u<<20)
#define WS_W3HI  ((size_t)96u<<20)
#define WS_W3LO  ((size_t)104u<<20)
#define WS_MISC  ((size_t)112u<<20)

// LDS: 2 buffers; within a buffer: Ahi at 0 (32KB), Alo at 32768 (32KB)
#define SEC_ALO 32768
#define BUFSZ   65536

__device__ __forceinline__ float sigmoidf_(float x) { return 1.0f / (1.0f + expf(-x)); }

__device__ __forceinline__ void glds16(const void* g, void* l) {
    __builtin_amdgcn_global_load_lds(
        (const __attribute__((address_space(1))) unsigned int*)g,
        (__attribute__((address_space(3))) unsigned int*)l, 16, 0, 0);
}

// Grid: 256 blocks (16 m x 16 hc). XCD-major over hc: 2MB weight slab/XCD.
__device__ __forceinline__ void block_tile(int& m0, int& hc0) {
    const int bid = blockIdx.x;
    const int lid = (bid & 7) * 32 + (bid >> 3);
    m0  = (lid & 15) * 256;
    hc0 = (lid >> 4) * 64;
}

// ---------------------------------------------------------------------------
// acc += A(256 rows x 1024) * B(256 vcols x 1024)^T, split-f16 3-product.
// A: pre-split f16 pairs, glds into LDS (128B rows, 8x16B slots, invariant:
//    slot s of row r holds k-chunk s^(r&7)) — proven zero-conflict.
// B_PAIR: fragment-PACKED hi/lo pairs -> coalesced 1KB loads (see header).
// !B_PAIR: fp32 row-major + split on the fly (stepA only, unchanged r9 path).
// ---------------------------------------------------------------------------
template<bool B_PAIR>
__device__ __forceinline__ void passK64(
    const f16* __restrict__ Ahi, const f16* __restrict__ Alo,
    const f16* __restrict__ Bhi, const f16* __restrict__ Blo,
    const float* __restrict__ Bf32,
    int m0, int hc0, f32x4 (&acc)[8][4], char* sm)
{
    const int tid = threadIdx.x, lane = tid & 63, wid = tid >> 6;
    const int wm  = (wid >> 2) * 128;
    const int wnb = wid & 3;
    const int l15 = lane & 15, lk = lane >> 4;

    // A fragment read offsets (per mf)
    int rbase[8], rx[8];
#pragma unroll
    for (int mf = 0; mf < 8; ++mf) {
        const int row = wm + mf * 16 + l15;
        rbase[mf] = row * 128;
        rx[mf]    = row & 7;
    }

    // A glds: 8 ops/wave. sec = wid>>2 (wave-uniform), j = (wid&3)*8 + i.
    const int secA = wid >> 2;
    const int j0   = (wid & 3) * 8;
    const int rl = lane >> 3, sl = lane & 7;
    const f16* gaBase = (secA ? Alo : Ahi)
                        + (size_t)(m0 + j0 * 8 + rl) * 1024 + ((sl ^ rl) << 3);
    const int albase0 = secA * SEC_ALO + j0 * 1024;

    // B base pointers
    const float* pB32 = nullptr;
    const f16* pwh = nullptr;
    const f16* pwl = nullptr;
    if constexpr (B_PAIR) {
        // packed: addr_f16 = (T*512 + wnb*4)*512 + kt*16384 + ks*8192 + nf*512 + lane*8
        const size_t pbase = ((size_t)((hc0 >> 6) * 512 + wnb * 4)) * 512 + (size_t)lane * 8;
        pwh = Bhi + pbase;
        pwl = Blo + pbase;
    } else {
        const int wrow0 = hc0 + wnb * 16 + l15;
        pB32 = Bf32 + (size_t)wrow0 * 1024 + lk * 8;
    }

    // B fragment register sets (named, static indexing)
    f16x8 bh0[4], bl0[4], bh1[4], bl1[4];
    float4 P[8];   // mixed-mode raw staging

    auto issueA = [&](int kt, char* buf) {
#pragma unroll
        for (int i = 0; i < 8; ++i)
            glds16(gaBase + (size_t)i * 8192 + kt * 64, buf + albase0 + i * 1024);
    };
    auto loadBP = [&](int kt, int ks, f16x8 (&H)[4], f16x8 (&L)[4]) {
        const size_t o = (size_t)kt * 16384 + (size_t)ks * 8192;
#pragma unroll
        for (int nf = 0; nf < 4; ++nf) {
            H[nf] = *(const f16x8*)(pwh + o + nf * 512);
            L[nf] = *(const f16x8*)(pwl + o + nf * 512);
        }
    };
    auto loadBM = [&](int kt, int ks) {
#pragma unroll
        for (int nf = 0; nf < 4; ++nf) {
            const float* p = pB32 + (size_t)nf * 1048576 + kt * 64 + ks * 32;
            P[2 * nf]     = *(const float4*)(p);
            P[2 * nf + 1] = *(const float4*)(p + 4);
        }
    };
    auto cvtM = [&](f16x8 (&H)[4], f16x8 (&L)[4]) {
#pragma unroll
        for (int nf = 0; nf < 4; ++nf) {
            const float* f0 = (const float*)&P[2 * nf];
            const float* f1 = (const float*)&P[2 * nf + 1];
            f16x8 h, l;
#pragma unroll
            for (int j = 0; j < 4; ++j) {
                const f16 a = (f16)f0[j];
                h[j] = a; l[j] = (f16)(f0[j] - (float)a);
                const f16 b = (f16)f1[j];
                h[4 + j] = b; l[4 + j] = (f16)(f1[j] - (float)b);
            }
            H[nf] = h; L[nf] = l;
        }
    };
    // product-major sweeps over 2-mf groups
    auto cluster = [&](const f16x8 (&BH)[4], const f16x8 (&BL)[4], int ks, char* bc) {
#pragma unroll
        for (int mg = 0; mg < 4; ++mg) {
            const int o0 = rbase[2 * mg]     + ((((ks << 2) | lk) ^ rx[2 * mg])     << 4);
            const int o1 = rbase[2 * mg + 1] + ((((ks << 2) | lk) ^ rx[2 * mg + 1]) << 4);
            const f16x8 ah0 = *(const f16x8*)(bc + o0);
            const f16x8 al0 = *(const f16x8*)(bc + SEC_ALO + o0);
            const f16x8 ah1 = *(const f16x8*)(bc + o1);
            const f16x8 al1 = *(const f16x8*)(bc + SEC_ALO + o1);
            __builtin_amdgcn_s_setprio(1);
#pragma unroll
            for (int nf = 0; nf < 4; ++nf) {
                acc[2 * mg][nf]     = __builtin_amdgcn_mfma_f32_16x16x32_f16(ah0, BH[nf], acc[2 * mg][nf], 0, 0, 0);
                acc[2 * mg + 1][nf] = __builtin_amdgcn_mfma_f32_16x16x32_f16(ah1, BH[nf], acc[2 * mg + 1][nf], 0, 0, 0);
            }
#pragma unroll
            for (int nf = 0; nf < 4; ++nf) {
                acc[2 * mg][nf]     = __builtin_amdgcn_mfma_f32_16x16x32_f16(ah0, BL[nf], acc[2 * mg][nf], 0, 0, 0);
                acc[2 * mg + 1][nf] = __builtin_amdgcn_mfma_f32_16x16x32_f16(ah1, BL[nf], acc[2 * mg + 1][nf], 0, 0, 0);
            }
#pragma unroll
            for (int nf = 0; nf < 4; ++nf) {
                acc[2 * mg][nf]     = __builtin_amdgcn_mfma_f32_16x16x32_f16(al0, BH[nf], acc[2 * mg][nf], 0, 0, 0);
                acc[2 * mg + 1][nf] = __builtin_amdgcn_mfma_f32_16x16x32_f16(al1, BH[nf], acc[2 * mg + 1][nf], 0, 0, 0);
            }
            __builtin_amdgcn_s_setprio(0);
        }
    };

    // ---- prologue ----
    if constexpr (B_PAIR) loadBP(0, 0, bh0, bl0);
    else                  loadBM(0, 0);
    issueA(0, sm);
    asm volatile("s_waitcnt vmcnt(0)" ::: "memory");
    __builtin_amdgcn_s_barrier();
    asm volatile("" ::: "memory");

#pragma unroll 1
    for (int kt = 0; kt < 16; ++kt) {
        char* bc = sm + (kt & 1) * BUFSZ;
        char* bn = sm + ((kt + 1) & 1) * BUFSZ;
        const bool pre = (kt < 15);

        if constexpr (B_PAIR) {
            loadBP(kt, 1, bh1, bl1);      // 8 oldest VMEM ops
            if (pre) issueA(kt + 1, bn);  // 8 glds (newer)
            cluster(bh0, bl0, 0, bc);
            if (pre) asm volatile("s_waitcnt vmcnt(8)" ::: "memory");  // bh1 ready
            else     asm volatile("s_waitcnt vmcnt(0)" ::: "memory");
            if (pre) loadBP(kt + 1, 0, bh0, bl0);
            cluster(bh1, bl1, 1, bc);
        } else {
            cvtM(bh0, bl0);               // P(ks0) -> frags, P dead
            loadBM(kt, 1);                // 8 oldest
            if (pre) issueA(kt + 1, bn);  // 8 glds (newer)
            cluster(bh0, bl0, 0, bc);
            if (pre) asm volatile("s_waitcnt vmcnt(8)" ::: "memory");  // P ready
            else     asm volatile("s_waitcnt vmcnt(0)" ::: "memory");
            cvtM(bh0, bl0);               // P(ks1) -> frags
            if (pre) loadBM(kt + 1, 0);
            cluster(bh0, bl0, 1, bc);
        }
        asm volatile("s_waitcnt vmcnt(0)" ::: "memory");  // glds ~2 clusters old
        if (pre) {
            __builtin_amdgcn_s_barrier();
            asm volatile("" ::: "memory");
        }
    }
}

// Z1 = x@W1^T + b_ih1 + b_hh1 (x pairs staged; W1 packed pairs direct-to-reg)
__global__ __launch_bounds__(512, 2) void k_z1(
    const f16* __restrict__ xhi, const f16* __restrict__ xlo,
    const f16* __restrict__ W1hi, const f16* __restrict__ W1lo,
    const float* __restrict__ bih1, const float* __restrict__ bhh1,
    float* __restrict__ Z1)
{
    __shared__ __align__(16) char sm[2 * BUFSZ];
    int m0, hc0; block_tile(m0, hc0);
    f32x4 acc[8][4];
#pragma unroll
    for (int a = 0; a < 8; ++a)
#pragma unroll
        for (int b = 0; b < 4; ++b) acc[a][b] = (f32x4){0.f, 0.f, 0.f, 0.f};
    passK64<true>(xhi, xlo, W1hi, W1lo, nullptr, m0, hc0, acc, sm);

    const int tid = threadIdx.x, lane = tid & 63, wid = tid >> 6;
    const int wm = (wid >> 2) * 128, wnb = wid & 3, l15 = lane & 15, lk = lane >> 4;
    const int hc = hc0 + wnb * 16 + l15;
#pragma unroll
    for (int mf = 0; mf < 8; ++mf)
#pragma unroll
        for (int r = 0; r < 4; ++r) {
            const int row = m0 + wm + mf * 16 + lk * 4 + r;
#pragma unroll
            for (int g = 0; g < 4; ++g) {
                const int R = g * 1024 + hc;
                Z1[(size_t)row * 4096 + R] = acc[mf][g][r] + bih1[R] + bhh1[R];
            }
        }
}

// Layer-1 cell: gates = Z1 (+flag col @step0) + h1@Whh1^T   (in-place h1/act)
__global__ __launch_bounds__(512, 2) void k_stepA(
    const float* __restrict__ Z1, const float* __restrict__ Whh1,
    const float* __restrict__ flagcol, float* __restrict__ c1,
    f16* __restrict__ h1hi, f16* __restrict__ h1lo,
    f16* __restrict__ acthi, f16* __restrict__ actlo,
    const unsigned* __restrict__ cnt_prev, int step)
{
    if (step > 0 && cnt_prev[0] == 0u) return;
    __shared__ __align__(16) char sm[2 * BUFSZ];
    int m0, hc0; block_tile(m0, hc0);
    f32x4 acc[8][4];
#pragma unroll
    for (int a = 0; a < 8; ++a)
#pragma unroll
        for (int b = 0; b < 4; ++b) acc[a][b] = (f32x4){0.f, 0.f, 0.f, 0.f};
    if (step > 0)
        passK64<false>(h1hi, h1lo, nullptr, nullptr, Whh1, m0, hc0, acc, sm);

    const int tid = threadIdx.x, lane = tid & 63, wid = tid >> 6;
    const int wm = (wid >> 2) * 128, wnb = wid & 3, l15 = lane & 15, lk = lane >> 4;
    const int hc = hc0 + wnb * 16 + l15;
#pragma unroll
    for (int mf = 0; mf < 8; ++mf)
#pragma unroll
        for (int r = 0; r < 4; ++r) {
            const int row = m0 + wm + mf * 16 + lk * 4 + r;
            float p[4];
#pragma unroll
            for (int g = 0; g < 4; ++g) {
                const int R = g * 1024 + hc;
                p[g] = acc[mf][g][r] + Z1[(size_t)row * 4096 + R];
                if (step == 0) p[g] += flagcol[R];
            }
            const float ig = sigmoidf_(p[0]);
            const float fg = sigmoidf_(p[1]);
            const float gg = tanhf(p[2]);
            const float og = sigmoidf_(p[3]);
            const int idx = row * 1024 + hc;
            const float cold = (step == 0) ? 0.0f : c1[idx];
            const float cn = fg * cold + ig * gg;
            c1[idx] = cn;
            const float h = og * tanhf(cn);
            const f16 hh = (f16)h;
            const f16 hl = (f16)(h - (float)hh);
            h1hi[idx] = hh; h1lo[idx] = hl;
            const bool pos = h > 0.0f;
            acthi[idx] = pos ? hh : (f16)0.0f;
            actlo[idx] = pos ? hl : (f16)0.0f;
        }
}

// Layer-2 cell: gates = b2 + act@Wih2^T + h2@Whh2^T (in-place h2; packed B)
__global__ __launch_bounds__(512, 2) void k_stepB(
    const f16* __restrict__ acthi, const f16* __restrict__ actlo,
    const f16* __restrict__ W2hi, const f16* __restrict__ W2lo,
    f16* __restrict__ h2hi, f16* __restrict__ h2lo,
    const f16* __restrict__ W3hi, const f16* __restrict__ W3lo,
    const float* __restrict__ bih2, const float* __restrict__ bhh2,
    float* __restrict__ c2,
    const unsigned* __restrict__ cnt_prev, int step)
{
    if (step > 0 && cnt_prev[0] == 0u) return;
    __shared__ __align__(16) char sm[2 * BUFSZ];
    int m0, hc0; block_tile(m0, hc0);
    f32x4 acc[8][4];
#pragma unroll
    for (int a = 0; a < 8; ++a)
#pragma unroll
        for (int b = 0; b < 4; ++b) acc[a][b] = (f32x4){0.f, 0.f, 0.f, 0.f};
    passK64<true>(acthi, actlo, W2hi, W2lo, nullptr, m0, hc0, acc, sm);
    if (step > 0)
        passK64<true>(h2hi, h2lo, W3hi, W3lo, nullptr, m0, hc0, acc, sm);

    const int tid = threadIdx.x, lane = tid & 63, wid = tid >> 6;
    const int wm = (wid >> 2) * 128, wnb = wid & 3, l15 = lane & 15, lk = lane >> 4;
    const int hc = hc0 + wnb * 16 + l15;
#pragma unroll
    for (int mf = 0; mf < 8; ++mf)
#pragma unroll
        for (int r = 0; r < 4; ++r) {
            const int row = m0 + wm + mf * 16 + lk * 4 + r;
            float p[4];
#pragma unroll
            for (int g = 0; g < 4; ++g) {
                const int R = g * 1024 + hc;
                p[g] = acc[mf][g][r] + bih2[R] + bhh2[R];
            }
            const float ig = sigmoidf_(p[0]);
            const float fg = sigmoidf_(p[1]);
            const float gg = tanhf(p[2]);
            const float og = sigmoidf_(p[3]);
            const int idx = row * 1024 + hc;
            const float cold = (step == 0) ? 0.0f : c2[idx];
            const float cn = fg * cold + ig * gg;
            c2[idx] = cn;
            const float h = og * tanhf(cn);
            const f16 hh = (f16)h;
            h2hi[idx] = hh;
            h2lo[idx] = (f16)(h - (float)hh);
        }
}

// Merged halting state machine + acc_out accumulate (one wave per row).
__global__ __launch_bounds__(256) void k_haltacc(
    const f16* __restrict__ h2hi, const f16* __restrict__ h2lo,
    const float* __restrict__ Whalt, const float* __restrict__ bhalt,
    float* __restrict__ halt, float* __restrict__ cont,
    float* __restrict__ ponder_out, unsigned* __restrict__ ctrl,
    float* __restrict__ acc_out,
    const unsigned* __restrict__ cnt_prev, int step)
{
    if (step > 0 && cnt_prev[0] == 0u) return;
    const int lane = threadIdx.x & 63;
    const int b = blockIdx.x * 4 + (threadIdx.x >> 6);
    const size_t base = (size_t)b * 1024;
    float sum = 0.0f;
    for (int k = lane; k < 1024; k += 64)
        sum += ((float)h2hi[base + k] + (float)h2lo[base + k]) * Whalt[k];
#pragma unroll
    for (int off = 32; off > 0; off >>= 1) sum += __shfl_down(sum, off, 64);
    float co = 0.0f;
    if (lane == 0) {
        const float sh = sigmoidf_(sum + bhalt[0]);
        if (cont[b] != 0.0f) {
            const float hn = halt[b] + sh;
            const bool ending = hn > 0.99f;
            co = sh + (ending ? (1.0f - hn) : 0.0f);
            halt[b] = hn;
            if (!ending) {
                ponder_out[b] += 1.0f;
                atomicAdd(&ctrl[step], 1u);
            } else {
                cont[b] = 0.0f;
            }
        }
    }
    co = __shfl(co, 0, 64);
    if (step == 0 || co != 0.0f) {
        float4* dst = (float4*)(acc_out + base);
        const f16x4* hi4 = (const f16x4*)(h2hi + base);
        const f16x4* lo4 = (const f16x4*)(h2lo + base);
#pragma unroll
        for (int j = 0; j < 4; ++j) {
            const int i = lane + 64 * j;
            const f16x4 hv = hi4[i];
            const f16x4 lv = lo4[i];
            float4 d = (step == 0) ? (float4){0.f, 0.f, 0.f, 0.f} : dst[i];
            d.x = fmaf(co, (float)hv[0] + (float)lv[0], d.x);
            d.y = fmaf(co, (float)hv[1] + (float)lv[1], d.y);
            d.z = fmaf(co, (float)hv[2] + (float)lv[2], d.z);
            d.w = fmaf(co, (float)hv[3] + (float)lv[3], d.w);
            dst[i] = d;
        }
    }
}

__global__ __launch_bounds__(256) void k_small_init(
    float* __restrict__ halt, float* __restrict__ cont,
    float* __restrict__ ponder_out, unsigned* __restrict__ ctrl)
{
    const int b = blockIdx.x * 256 + threadIdx.x;
    if (b < 4096) { halt[b] = 0.0f; cont[b] = 1.0f; ponder_out[b] = 0.0f; }
    if (b < 16) ctrl[b] = 0u;
}

// flat fp32 -> f16 hi/lo pairs, standard row-major (A-side: inputs x)
__global__ __launch_bounds__(256) void k_split_flat(
    const float* __restrict__ src, f16* __restrict__ hi, f16* __restrict__ lo)
{
    const size_t i = ((size_t)blockIdx.x * 256 + threadIdx.x) * 4;
    const float4 v = *(const float4*)(src + i);
    const f16 s0 = (f16)v.x, s1 = (f16)v.y, s2 = (f16)v.z, s3 = (f16)v.w;
    const f16x4 hv = {s0, s1, s2, s3};
    const f16x4 lw = {(f16)(v.x - (float)s0), (f16)(v.y - (float)s1),
                      (f16)(v.z - (float)s2), (f16)(v.w - (float)s3)};
    *(f16x4*)(hi + i) = hv;
    *(f16x4*)(lo + i) = lw;
}

// Weight -> fragment-PACKED f16 hi/lo pairs.
// t = C*64 + lane; C = T*512 + kt*32 + ks*16 + wnb*4 + nf.
// src row = nf*1024 + T*64 + wnb*16 + (lane&15); k0 = kt*64+ks*32+(lane>>4)*8.
__global__ __launch_bounds__(256) void k_pack_w(
    const float* __restrict__ src, f16* __restrict__ hi, f16* __restrict__ lo,
    int stride)
{
    const size_t t = (size_t)blockIdx.x * 256 + threadIdx.x;   // 524288 total
    const int lane = (int)(t & 63);
    const size_t C = t >> 6;
    const int nf  = (int)(C & 3);
    const int wnb = (int)((C >> 2) & 3);
    const int ks  = (int)((C >> 4) & 1);
    const int kt  = (int)((C >> 5) & 15);
    const int T   = (int)(C >> 9);
    const int row = nf * 1024 + T * 64 + wnb * 16 + (lane & 15);
    const int k0  = kt * 64 + ks * 32 + (lane >> 4) * 8;
    const float* s = src + (size_t)row * stride + k0;
    f16x8 h, l;
#pragma unroll
    for (int j = 0; j < 8; ++j) {
        const float v = s[j];
        const f16 a = (f16)v;
        h[j] = a; l[j] = (f16)(v - (float)a);
    }
    *(f16x8*)(hi + t * 8) = h;
    *(f16x8*)(lo + t * 8) = l;
}

// extract W_ih1 column 1024 (flag column)
__global__ __launch_bounds__(256) void k_flagcol(
    const float* __restrict__ Wih1, float* __restrict__ flagcol)
{
    const int r = blockIdx.x * 256 + threadIdx.x;
    if (r < 4096) flagcol[r] = Wih1[(size_t)r * 1025 + 1024];
}

// finalize: states to d_out + remainder term
__global__ __launch_bounds__(256) void k_fin1(
    const f16* __restrict__ h1hi, const f16* __restrict__ h1lo,
    const f16* __restrict__ h2hi, const f16* __restrict__ h2lo,
    const float* __restrict__ c1s, const float* __restrict__ c2s,
    const float* __restrict__ halt, const float* __restrict__ cont,
    float* __restrict__ out)
{
    const int b = blockIdx.x;
    const float rem = (cont[b] != 0.0f) ? (1.0f - halt[b]) : 0.0f;
    const int base = b * 1024;
    for (int i = threadIdx.x; i < 1024; i += 256) {
        const float h1v = (float)h1hi[base + i] + (float)h1lo[base + i];
        const float h2v = (float)h2hi[base + i] + (float)h2lo[base + i];
        out[O_H1 + base + i] = h1v;
        out[O_C1 + base + i] = c1s[base + i];
        out[O_H2 + base + i] = h2v;
        out[O_C2 + base + i] = c2s[base + i];
        if (rem != 0.0f) out[O_ACC + base + i] += rem * h2v;
    }
}

__global__ __launch_bounds__(256) void k_fin2(
    const float* __restrict__ halt, float* __restrict__ out)
{
    __shared__ float red[256];
    float s = 0.0f;
    for (int i = threadIdx.x; i < 4096; i += 256) s += halt[i];
    red[threadIdx.x] = s;
    __syncthreads();
    for (int w = 128; w > 0; w >>= 1) {
        if (threadIdx.x < w) red[threadIdx.x] += red[threadIdx.x + w];
        __syncthreads();
    }
    if (threadIdx.x == 0) out[O_PCOST] = -0.01f * (red[0] * (1.0f / 4096.0f));
}

extern "C" void kernel_launch(void* const* d_in, const int* in_sizes, int n_in,
                              void* d_out, int out_size, void* d_ws, size_t ws_size,
                              hipStream_t stream) {
    const float* inputs = (const float*)d_in[0];
    const float* W_ih1  = (const float*)d_in[1];
    const float* W_hh1  = (const float*)d_in[2];
    const float* b_ih1  = (const float*)d_in[3];
    const float* b_hh1  = (const float*)d_in[4];
    const float* W_ih2  = (const float*)d_in[5];
    const float* W_hh2  = (const float*)d_in[6];
    const float* b_ih2  = (const float*)d_in[7];
    const float* b_hh2  = (const float*)d_in[8];
    const float* W_halt = (const float*)d_in[9];
    const float* b_halt = (const float*)d_in[10];

    float* out = (float*)d_out;
    float* Z1  = out + O_H1;                  // 64 MB in d_out's dead state region

    char* wsb = (char*)d_ws;
    float* c1s = (float*)(wsb + WS_C1);
    float* c2s = (float*)(wsb + WS_C2);
    f16* h1hi = (f16*)(wsb + WS_H1HI);
    f16* h1lo = (f16*)(wsb + WS_H1LO);
    f16* h2hi = (f16*)(wsb + WS_H2HI);
    f16* h2lo = (f16*)(wsb + WS_H2LO);
    f16* acthi = (f16*)(wsb + WS_ACTHI);
    f16* actlo = (f16*)(wsb + WS_ACTLO);
    f16* W2hi = (f16*)(wsb + WS_W2HI);
    f16* W2lo = (f16*)(wsb + WS_W2LO);
    f16* W3hi = (f16*)(wsb + WS_W3HI);
    f16* W3lo = (f16*)(wsb + WS_W3LO);
    float* halt    = (float*)(wsb + WS_MISC);
    float* cont    = halt + 4096;
    float* flagcol = cont + 4096;
    unsigned* ctrl = (unsigned*)(flagcol + 4096);

    // z1 temporaries in step-0-dead state slots: x pairs in h1, W1 pairs in h2
    f16* xhi  = h1hi; f16* xlo  = h1lo;
    f16* W1hi = h2hi; f16* W1lo = h2lo;

    k_small_init<<<16, 256, 0, stream>>>(halt, cont, out + O_PSTEP, ctrl);

    k_flagcol<<<16, 256, 0, stream>>>(W_ih1, flagcol);
    k_pack_w<<<2048, 256, 0, stream>>>(W_ih1, W1hi, W1lo, 1025);
    k_pack_w<<<2048, 256, 0, stream>>>(W_ih2, W2hi, W2lo, 1024);
    k_pack_w<<<2048, 256, 0, stream>>>(W_hh2, W3hi, W3lo, 1024);
    k_split_flat<<<4096, 256, 0, stream>>>(inputs, xhi, xlo);
    k_z1<<<256, 512, 0, stream>>>(xhi, xlo, W1hi, W1lo, b_ih1, b_hh1, Z1);

    for (int s = 0; s < TSTEPS; ++s) {
        const unsigned* cnt_prev = ctrl + (s > 0 ? s - 1 : 0);

        k_stepA<<<256, 512, 0, stream>>>(Z1, W_hh1, flagcol, c1s,
                                         h1hi, h1lo, acthi, actlo,
                                         cnt_prev, s);
        k_stepB<<<256, 512, 0, stream>>>(acthi, actlo, W2hi, W2lo,
                                         h2hi, h2lo, W3hi, W3lo,
                                         b_ih2, b_hh2, c2s,
                                         cnt_prev, s);
        k_haltacc<<<1024, 256, 0, stream>>>(h2hi, h2lo, W_halt, b_halt,
                                            halt, cont, out + O_PSTEP, ctrl,
                                            out + O_ACC, cnt_prev, s);
    }

    k_fin1<<<4096, 256, 0, stream>>>(h1hi, h1lo, h2hi, h2lo,
                                     c1s, c2s, halt, cont, out);
    k_fin2<<<1, 256, 0, stream>>>(halt, out);
}

// Round 12
// 1369.028 us; speedup vs baseline: 1.3729x; 1.0334x over previous
//
#include <hip/hip_runtime.h>
#include <cstdint>
#include <cstddef>

// ---------------------------------------------------------------------------
// AdaptiveLSTMBlockWrapper — round 12: R11 + (a) packed Whh1 for stepA (runtime
// ws_size-guarded; fallback = r11 mixed path), (b) counted end-of-kt vmcnt(8)
// so next-kt B loads stay in flight across the barrier (never drain to 0).
//
// Packed-weight layout (proven r11): chunk C = T*512 + kt*32 + ks*16 + wnb*4
// + nf; bytes [C][lane][16B]; B fragment load = base + C*1024 + lane*16 (one
// coalesced 1KB transaction). A-side: pre-split f16 pairs glds'd into LDS
// (128B rows, 8x16B slots, slot^(row&7) — proven 0-conflict), BK=64,
// 1 barrier/kt, product-major 3-product split-f16 MFMA, setprio on sweeps.
// ---------------------------------------------------------------------------

typedef _Float16 f16;
typedef f16   f16x8 __attribute__((ext_vector_type(8)));
typedef f16   f16x4 __attribute__((ext_vector_type(4)));
typedef float f32x4 __attribute__((ext_vector_type(4)));

#define TSTEPS 12

// d_out float offsets
#define O_ACC   0u
#define O_H1    4194304u
#define O_C1    8388608u
#define O_H2    12582912u
#define O_C2    16777216u
#define O_PCOST 20971520u
#define O_PSTEP 20971521u

// ws byte offsets
#define WS_C1    ((size_t)0u)
#define WS_C2    ((size_t)16u<<20)
#define WS_H1HI  ((size_t)32u<<20)
#define WS_H1LO  ((size_t)40u<<20)
#define WS_H2HI  ((size_t)48u<<20)
#define WS_H2LO  ((size_t)56u<<20)
#define WS_ACTHI ((size_t)64u<<20)
#define WS_ACTLO ((size_t)72u<<20)
#define WS_W2HI  ((size_t)80u<<20)
#define WS_W2LO  ((size_t)88u<<20)
#define WS_W3HI  ((size_t)96u<<20)
#define WS_W3LO  ((size_t)104u<<20)
#define WS_MISC  ((size_t)112u<<20)
// optional (only if ws_size >= WS_NEED_PACKA): packed Whh1 pairs
#define WS_W4HI  ((size_t)113u<<20)
#define WS_W4LO  ((size_t)121u<<20)
#define WS_NEED_PACKA ((size_t)129u<<20)

// LDS: 2 buffers; within a buffer: Ahi at 0 (32KB), Alo at 32768 (32KB)
#define SEC_ALO 32768
#define BUFSZ   65536

__device__ __forceinline__ float sigmoidf_(float x) { return 1.0f / (1.0f + expf(-x)); }

__device__ __forceinline__ void glds16(const void* g, void* l) {
    __builtin_amdgcn_global_load_lds(
        (const __attribute__((address_space(1))) unsigned int*)g,
        (__attribute__((address_space(3))) unsigned int*)l, 16, 0, 0);
}

// Grid: 256 blocks (16 m x 16 hc). XCD-major over hc: 2MB weight slab/XCD.
__device__ __forceinline__ void block_tile(int& m0, int& hc0) {
    const int bid = blockIdx.x;
    const int lid = (bid & 7) * 32 + (bid >> 3);
    m0  = (lid & 15) * 256;
    hc0 = (lid >> 4) * 64;
}

// ---------------------------------------------------------------------------
// acc += A(256 rows x 1024) * B(256 vcols x 1024)^T, split-f16 3-product.
// B_PAIR: fragment-packed hi/lo pairs (coalesced 1KB loads).
// !B_PAIR: fp32 row-major gather + split on the fly (fallback stepA only).
// Counted waits: mid-kt and end-of-kt both vmcnt(8) while prefetching —
// only the epilogue kt drains to 0.
// ---------------------------------------------------------------------------
template<bool B_PAIR>
__device__ __forceinline__ void passK64(
    const f16* __restrict__ Ahi, const f16* __restrict__ Alo,
    const f16* __restrict__ Bhi, const f16* __restrict__ Blo,
    const float* __restrict__ Bf32,
    int m0, int hc0, f32x4 (&acc)[8][4], char* sm)
{
    const int tid = threadIdx.x, lane = tid & 63, wid = tid >> 6;
    const int wm  = (wid >> 2) * 128;
    const int wnb = wid & 3;
    const int l15 = lane & 15, lk = lane >> 4;

    // A fragment read offsets (per mf)
    int rbase[8], rx[8];
#pragma unroll
    for (int mf = 0; mf < 8; ++mf) {
        const int row = wm + mf * 16 + l15;
        rbase[mf] = row * 128;
        rx[mf]    = row & 7;
    }

    // A glds: 8 ops/wave. sec = wid>>2 (wave-uniform), j = (wid&3)*8 + i.
    const int secA = wid >> 2;
    const int j0   = (wid & 3) * 8;
    const int rl = lane >> 3, sl = lane & 7;
    const f16* gaBase = (secA ? Alo : Ahi)
                        + (size_t)(m0 + j0 * 8 + rl) * 1024 + ((sl ^ rl) << 3);
    const int albase0 = secA * SEC_ALO + j0 * 1024;

    // B base pointers
    const float* pB32 = nullptr;
    const f16* pwh = nullptr;
    const f16* pwl = nullptr;
    if constexpr (B_PAIR) {
        const size_t pbase = ((size_t)((hc0 >> 6) * 512 + wnb * 4)) * 512 + (size_t)lane * 8;
        pwh = Bhi + pbase;
        pwl = Blo + pbase;
    } else {
        const int wrow0 = hc0 + wnb * 16 + l15;
        pB32 = Bf32 + (size_t)wrow0 * 1024 + lk * 8;
    }

    // B fragment register sets (named, static indexing)
    f16x8 bh0[4], bl0[4], bh1[4], bl1[4];
    float4 P[8];   // mixed-mode raw staging

    auto issueA = [&](int kt, char* buf) {
#pragma unroll
        for (int i = 0; i < 8; ++i)
            glds16(gaBase + (size_t)i * 8192 + kt * 64, buf + albase0 + i * 1024);
    };
    auto loadBP = [&](int kt, int ks, f16x8 (&H)[4], f16x8 (&L)[4]) {
        const size_t o = (size_t)kt * 16384 + (size_t)ks * 8192;
#pragma unroll
        for (int nf = 0; nf < 4; ++nf) {
            H[nf] = *(const f16x8*)(pwh + o + nf * 512);
            L[nf] = *(const f16x8*)(pwl + o + nf * 512);
        }
    };
    auto loadBM = [&](int kt, int ks) {
#pragma unroll
        for (int nf = 0; nf < 4; ++nf) {
            const float* p = pB32 + (size_t)nf * 1048576 + kt * 64 + ks * 32;
            P[2 * nf]     = *(const float4*)(p);
            P[2 * nf + 1] = *(const float4*)(p + 4);
        }
    };
    auto cvtM = [&](f16x8 (&H)[4], f16x8 (&L)[4]) {
#pragma unroll
        for (int nf = 0; nf < 4; ++nf) {
            const float* f0 = (const float*)&P[2 * nf];
            const float* f1 = (const float*)&P[2 * nf + 1];
            f16x8 h, l;
#pragma unroll
            for (int j = 0; j < 4; ++j) {
                const f16 a = (f16)f0[j];
                h[j] = a; l[j] = (f16)(f0[j] - (float)a);
                const f16 b = (f16)f1[j];
                h[4 + j] = b; l[4 + j] = (f16)(f1[j] - (float)b);
            }
            H[nf] = h; L[nf] = l;
        }
    };
    // product-major sweeps over 2-mf groups
    auto cluster = [&](const f16x8 (&BH)[4], const f16x8 (&BL)[4], int ks, char* bc) {
#pragma unroll
        for (int mg = 0; mg < 4; ++mg) {
            const int o0 = rbase[2 * mg]     + ((((ks << 2) | lk) ^ rx[2 * mg])     << 4);
            const int o1 = rbase[2 * mg + 1] + ((((ks << 2) | lk) ^ rx[2 * mg + 1]) << 4);
            const f16x8 ah0 = *(const f16x8*)(bc + o0);
            const f16x8 al0 = *(const f16x8*)(bc + SEC_ALO + o0);
            const f16x8 ah1 = *(const f16x8*)(bc + o1);
            const f16x8 al1 = *(const f16x8*)(bc + SEC_ALO + o1);
            __builtin_amdgcn_s_setprio(1);
#pragma unroll
            for (int nf = 0; nf < 4; ++nf) {
                acc[2 * mg][nf]     = __builtin_amdgcn_mfma_f32_16x16x32_f16(ah0, BH[nf], acc[2 * mg][nf], 0, 0, 0);
                acc[2 * mg + 1][nf] = __builtin_amdgcn_mfma_f32_16x16x32_f16(ah1, BH[nf], acc[2 * mg + 1][nf], 0, 0, 0);
            }
#pragma unroll
            for (int nf = 0; nf < 4; ++nf) {
                acc[2 * mg][nf]     = __builtin_amdgcn_mfma_f32_16x16x32_f16(ah0, BL[nf], acc[2 * mg][nf], 0, 0, 0);
                acc[2 * mg + 1][nf] = __builtin_amdgcn_mfma_f32_16x16x32_f16(ah1, BL[nf], acc[2 * mg + 1][nf], 0, 0, 0);
            }
#pragma unroll
            for (int nf = 0; nf < 4; ++nf) {
                acc[2 * mg][nf]     = __builtin_amdgcn_mfma_f32_16x16x32_f16(al0, BH[nf], acc[2 * mg][nf], 0, 0, 0);
                acc[2 * mg + 1][nf] = __builtin_amdgcn_mfma_f32_16x16x32_f16(al1, BH[nf], acc[2 * mg + 1][nf], 0, 0, 0);
            }
            __builtin_amdgcn_s_setprio(0);
        }
    };

    // ---- prologue ----
    if constexpr (B_PAIR) loadBP(0, 0, bh0, bl0);
    else                  loadBM(0, 0);
    issueA(0, sm);
    asm volatile("s_waitcnt vmcnt(0)" ::: "memory");
    __builtin_amdgcn_s_barrier();
    asm volatile("" ::: "memory");

#pragma unroll 1
    for (int kt = 0; kt < 16; ++kt) {
        char* bc = sm + (kt & 1) * BUFSZ;
        char* bn = sm + ((kt + 1) & 1) * BUFSZ;
        const bool pre = (kt < 15);

        if constexpr (B_PAIR) {
            loadBP(kt, 1, bh1, bl1);      // 8 oldest VMEM ops
            if (pre) issueA(kt + 1, bn);  // 8 glds (newer)
            cluster(bh0, bl0, 0, bc);
            if (pre) asm volatile("s_waitcnt vmcnt(8)" ::: "memory");  // bh1 ready
            else     asm volatile("s_waitcnt vmcnt(0)" ::: "memory");
            if (pre) loadBP(kt + 1, 0, bh0, bl0);
            cluster(bh1, bl1, 1, bc);
        } else {
            cvtM(bh0, bl0);               // P(ks0) -> frags, P dead
            loadBM(kt, 1);                // 8 oldest
            if (pre) issueA(kt + 1, bn);  // 8 glds (newer)
            cluster(bh0, bl0, 0, bc);
            if (pre) asm volatile("s_waitcnt vmcnt(8)" ::: "memory");  // P ready
            else     asm volatile("s_waitcnt vmcnt(0)" ::: "memory");
            cvtM(bh0, bl0);               // P(ks1) -> frags
            if (pre) loadBM(kt + 1, 0);
            cluster(bh0, bl0, 1, bc);
        }
        // end-of-kt: retire only the glds (oldest 8); next-kt B loads stay
        // in flight across the barrier (compiler waits on first use).
        if (pre) {
            asm volatile("s_waitcnt vmcnt(8)" ::: "memory");
            __builtin_amdgcn_s_barrier();
            asm volatile("" ::: "memory");
        } else {
            asm volatile("s_waitcnt vmcnt(0)" ::: "memory");
        }
    }
}

// Z1 = x@W1^T + b_ih1 + b_hh1 (x pairs staged; W1 packed pairs direct-to-reg)
__global__ __launch_bounds__(512, 2) void k_z1(
    const f16* __restrict__ xhi, const f16* __restrict__ xlo,
    const f16* __restrict__ W1hi, const f16* __restrict__ W1lo,
    const float* __restrict__ bih1, const float* __restrict__ bhh1,
    float* __restrict__ Z1)
{
    __shared__ __align__(16) char sm[2 * BUFSZ];
    int m0, hc0; block_tile(m0, hc0);
    f32x4 acc[8][4];
#pragma unroll
    for (int a = 0; a < 8; ++a)
#pragma unroll
        for (int b = 0; b < 4; ++b) acc[a][b] = (f32x4){0.f, 0.f, 0.f, 0.f};
    passK64<true>(xhi, xlo, W1hi, W1lo, nullptr, m0, hc0, acc, sm);

    const int tid = threadIdx.x, lane = tid & 63, wid = tid >> 6;
    const int wm = (wid >> 2) * 128, wnb = wid & 3, l15 = lane & 15, lk = lane >> 4;
    const int hc = hc0 + wnb * 16 + l15;
#pragma unroll
    for (int mf = 0; mf < 8; ++mf)
#pragma unroll
        for (int r = 0; r < 4; ++r) {
            const int row = m0 + wm + mf * 16 + lk * 4 + r;
#pragma unroll
            for (int g = 0; g < 4; ++g) {
                const int R = g * 1024 + hc;
                Z1[(size_t)row * 4096 + R] = acc[mf][g][r] + bih1[R] + bhh1[R];
            }
        }
}

// Layer-1 cell: gates = Z1 (+flag col @step0) + h1@Whh1^T  (in-place h1/act)
// PACKED: Whh1 fragment-packed pairs; else r11 fp32-gather fallback.
template<bool PACKED>
__global__ __launch_bounds__(512, 2) void k_stepA(
    const float* __restrict__ Z1, const float* __restrict__ Whh1,
    const f16* __restrict__ W4hi, const f16* __restrict__ W4lo,
    const float* __restrict__ flagcol, float* __restrict__ c1,
    f16* __restrict__ h1hi, f16* __restrict__ h1lo,
    f16* __restrict__ acthi, f16* __restrict__ actlo,
    const unsigned* __restrict__ cnt_prev, int step)
{
    if (step > 0 && cnt_prev[0] == 0u) return;
    __shared__ __align__(16) char sm[2 * BUFSZ];
    int m0, hc0; block_tile(m0, hc0);
    f32x4 acc[8][4];
#pragma unroll
    for (int a = 0; a < 8; ++a)
#pragma unroll
        for (int b = 0; b < 4; ++b) acc[a][b] = (f32x4){0.f, 0.f, 0.f, 0.f};
    if (step > 0) {
        if constexpr (PACKED)
            passK64<true>(h1hi, h1lo, W4hi, W4lo, nullptr, m0, hc0, acc, sm);
        else
            passK64<false>(h1hi, h1lo, nullptr, nullptr, Whh1, m0, hc0, acc, sm);
    }

    const int tid = threadIdx.x, lane = tid & 63, wid = tid >> 6;
    const int wm = (wid >> 2) * 128, wnb = wid & 3, l15 = lane & 15, lk = lane >> 4;
    const int hc = hc0 + wnb * 16 + l15;
#pragma unroll
    for (int mf = 0; mf < 8; ++mf)
#pragma unroll
        for (int r = 0; r < 4; ++r) {
            const int row = m0 + wm + mf * 16 + lk * 4 + r;
            float p[4];
#pragma unroll
            for (int g = 0; g < 4; ++g) {
                const int R = g * 1024 + hc;
                p[g] = acc[mf][g][r] + Z1[(size_t)row * 4096 + R];
                if (step == 0) p[g] += flagcol[R];
            }
            const float ig = sigmoidf_(p[0]);
            const float fg = sigmoidf_(p[1]);
            const float gg = tanhf(p[2]);
            const float og = sigmoidf_(p[3]);
            const int idx = row * 1024 + hc;
            const float cold = (step == 0) ? 0.0f : c1[idx];
            const float cn = fg * cold + ig * gg;
            c1[idx] = cn;
            const float h = og * tanhf(cn);
            const f16 hh = (f16)h;
            const f16 hl = (f16)(h - (float)hh);
            h1hi[idx] = hh; h1lo[idx] = hl;
            const bool pos = h > 0.0f;
            acthi[idx] = pos ? hh : (f16)0.0f;
            actlo[idx] = pos ? hl : (f16)0.0f;
        }
}

// Layer-2 cell: gates = b2 + act@Wih2^T + h2@Whh2^T (in-place h2; packed B)
__global__ __launch_bounds__(512, 2) void k_stepB(
    const f16* __restrict__ acthi, const f16* __restrict__ actlo,
    const f16* __restrict__ W2hi, const f16* __restrict__ W2lo,
    f16* __restrict__ h2hi, f16* __restrict__ h2lo,
    const f16* __restrict__ W3hi, const f16* __restrict__ W3lo,
    const float* __restrict__ bih2, const float* __restrict__ bhh2,
    float* __restrict__ c2,
    const unsigned* __restrict__ cnt_prev, int step)
{
    if (step > 0 && cnt_prev[0] == 0u) return;
    __shared__ __align__(16) char sm[2 * BUFSZ];
    int m0, hc0; block_tile(m0, hc0);
    f32x4 acc[8][4];
#pragma unroll
    for (int a = 0; a < 8; ++a)
#pragma unroll
        for (int b = 0; b < 4; ++b) acc[a][b] = (f32x4){0.f, 0.f, 0.f, 0.f};
    passK64<true>(acthi, actlo, W2hi, W2lo, nullptr, m0, hc0, acc, sm);
    if (step > 0)
        passK64<true>(h2hi, h2lo, W3hi, W3lo, nullptr, m0, hc0, acc, sm);

    const int tid = threadIdx.x, lane = tid & 63, wid = tid >> 6;
    const int wm = (wid >> 2) * 128, wnb = wid & 3, l15 = lane & 15, lk = lane >> 4;
    const int hc = hc0 + wnb * 16 + l15;
#pragma unroll
    for (int mf = 0; mf < 8; ++mf)
#pragma unroll
        for (int r = 0; r < 4; ++r) {
            const int row = m0 + wm + mf * 16 + lk * 4 + r;
            float p[4];
#pragma unroll
            for (int g = 0; g < 4; ++g) {
                const int R = g * 1024 + hc;
                p[g] = acc[mf][g][r] + bih2[R] + bhh2[R];
            }
            const float ig = sigmoidf_(p[0]);
            const float fg = sigmoidf_(p[1]);
            const float gg = tanhf(p[2]);
            const float og = sigmoidf_(p[3]);
            const int idx = row * 1024 + hc;
            const float cold = (step == 0) ? 0.0f : c2[idx];
            const float cn = fg * cold + ig * gg;
            c2[idx] = cn;
            const float h = og * tanhf(cn);
            const f16 hh = (f16)h;
            h2hi[idx] = hh;
            h2lo[idx] = (f16)(h - (float)hh);
        }
}

// Merged halting state machine + acc_out accumulate (one wave per row).
__global__ __launch_bounds__(256) void k_haltacc(
    const f16* __restrict__ h2hi, const f16* __restrict__ h2lo,
    const float* __restrict__ Whalt, const float* __restrict__ bhalt,
    float* __restrict__ halt, float* __restrict__ cont,
    float* __restrict__ ponder_out, unsigned* __restrict__ ctrl,
    float* __restrict__ acc_out,
    const unsigned* __restrict__ cnt_prev, int step)
{
    if (step > 0 && cnt_prev[0] == 0u) return;
    const int lane = threadIdx.x & 63;
    const int b = blockIdx.x * 4 + (threadIdx.x >> 6);
    const size_t base = (size_t)b * 1024;
    float sum = 0.0f;
    for (int k = lane; k < 1024; k += 64)
        sum += ((float)h2hi[base + k] + (float)h2lo[base + k]) * Whalt[k];
#pragma unroll
    for (int off = 32; off > 0; off >>= 1) sum += __shfl_down(sum, off, 64);
    float co = 0.0f;
    if (lane == 0) {
        const float sh = sigmoidf_(sum + bhalt[0]);
        if (cont[b] != 0.0f) {
            const float hn = halt[b] + sh;
            const bool ending = hn > 0.99f;
            co = sh + (ending ? (1.0f - hn) : 0.0f);
            halt[b] = hn;
            if (!ending) {
                ponder_out[b] += 1.0f;
                atomicAdd(&ctrl[step], 1u);
            } else {
                cont[b] = 0.0f;
            }
        }
    }
    co = __shfl(co, 0, 64);
    if (step == 0 || co != 0.0f) {
        float4* dst = (float4*)(acc_out + base);
        const f16x4* hi4 = (const f16x4*)(h2hi + base);
        const f16x4* lo4 = (const f16x4*)(h2lo + base);
#pragma unroll
        for (int j = 0; j < 4; ++j) {
            const int i = lane + 64 * j;
            const f16x4 hv = hi4[i];
            const f16x4 lv = lo4[i];
            float4 d = (step == 0) ? (float4){0.f, 0.f, 0.f, 0.f} : dst[i];
            d.x = fmaf(co, (float)hv[0] + (float)lv[0], d.x);
            d.y = fmaf(co, (float)hv[1] + (float)lv[1], d.y);
            d.z = fmaf(co, (float)hv[2] + (float)lv[2], d.z);
            d.w = fmaf(co, (float)hv[3] + (float)lv[3], d.w);
            dst[i] = d;
        }
    }
}

__global__ __launch_bounds__(256) void k_small_init(
    float* __restrict__ halt, float* __restrict__ cont,
    float* __restrict__ ponder_out, unsigned* __restrict__ ctrl)
{
    const int b = blockIdx.x * 256 + threadIdx.x;
    if (b < 4096) { halt[b] = 0.0f; cont[b] = 1.0f; ponder_out[b] = 0.0f; }
    if (b < 16) ctrl[b] = 0u;
}

// flat fp32 -> f16 hi/lo pairs, standard row-major (A-side: inputs x)
__global__ __launch_bounds__(256) void k_split_flat(
    const float* __restrict__ src, f16* __restrict__ hi, f16* __restrict__ lo)
{
    const size_t i = ((size_t)blockIdx.x * 256 + threadIdx.x) * 4;
    const float4 v = *(const float4*)(src + i);
    const f16 s0 = (f16)v.x, s1 = (f16)v.y, s2 = (f16)v.z, s3 = (f16)v.w;
    const f16x4 hv = {s0, s1, s2, s3};
    const f16x4 lw = {(f16)(v.x - (float)s0), (f16)(v.y - (float)s1),
                      (f16)(v.z - (float)s2), (f16)(v.w - (float)s3)};
    *(f16x4*)(hi + i) = hv;
    *(f16x4*)(lo + i) = lw;
}

// Weight -> fragment-PACKED f16 hi/lo pairs.
// t = C*64 + lane; C = T*512 + kt*32 + ks*16 + wnb*4 + nf.
// src row = nf*1024 + T*64 + wnb*16 + (lane&15); k0 = kt*64+ks*32+(lane>>4)*8.
__global__ __launch_bounds__(256) void k_pack_w(
    const float* __restrict__ src, f16* __restrict__ hi, f16* __restrict__ lo,
    int stride)
{
    const size_t t = (size_t)blockIdx.x * 256 + threadIdx.x;   // 524288 total
    const int lane = (int)(t & 63);
    const size_t C = t >> 6;
    const int nf  = (int)(C & 3);
    const int wnb = (int)((C >> 2) & 3);
    const int ks  = (int)((C >> 4) & 1);
    const int kt  = (int)((C >> 5) & 15);
    const int T   = (int)(C >> 9);
    const int row = nf * 1024 + T * 64 + wnb * 16 + (lane & 15);
    const int k0  = kt * 64 + ks * 32 + (lane >> 4) * 8;
    const float* s = src + (size_t)row * stride + k0;
    f16x8 h, l;
#pragma unroll
    for (int j = 0; j < 8; ++j) {
        const float v = s[j];
        const f16 a = (f16)v;
        h[j] = a; l[j] = (f16)(v - (float)a);
    }
    *(f16x8*)(hi + t * 8) = h;
    *(f16x8*)(lo + t * 8) = l;
}

// extract W_ih1 column 1024 (flag column)
__global__ __launch_bounds__(256) void k_flagcol(
    const float* __restrict__ Wih1, float* __restrict__ flagcol)
{
    const int r = blockIdx.x * 256 + threadIdx.x;
    if (r < 4096) flagcol[r] = Wih1[(size_t)r * 1025 + 1024];
}

// finalize: states to d_out + remainder term
__global__ __launch_bounds__(256) void k_fin1(
    const f16* __restrict__ h1hi, const f16* __restrict__ h1lo,
    const f16* __restrict__ h2hi, const f16* __restrict__ h2lo,
    const float* __restrict__ c1s, const float* __restrict__ c2s,
    const float* __restrict__ halt, const float* __restrict__ cont,
    float* __restrict__ out)
{
    const int b = blockIdx.x;
    const float rem = (cont[b] != 0.0f) ? (1.0f - halt[b]) : 0.0f;
    const int base = b * 1024;
    for (int i = threadIdx.x; i < 1024; i += 256) {
        const float h1v = (float)h1hi[base + i] + (float)h1lo[base + i];
        const float h2v = (float)h2hi[base + i] + (float)h2lo[base + i];
        out[O_H1 + base + i] = h1v;
        out[O_C1 + base + i] = c1s[base + i];
        out[O_H2 + base + i] = h2v;
        out[O_C2 + base + i] = c2s[base + i];
        if (rem != 0.0f) out[O_ACC + base + i] += rem * h2v;
    }
}

__global__ __launch_bounds__(256) void k_fin2(
    const float* __restrict__ halt, float* __restrict__ out)
{
    __shared__ float red[256];
    float s = 0.0f;
    for (int i = threadIdx.x; i < 4096; i += 256) s += halt[i];
    red[threadIdx.x] = s;
    __syncthreads();
    for (int w = 128; w > 0; w >>= 1) {
        if (threadIdx.x < w) red[threadIdx.x] += red[threadIdx.x + w];
        __syncthreads();
    }
    if (threadIdx.x == 0) out[O_PCOST] = -0.01f * (red[0] * (1.0f / 4096.0f));
}

extern "C" void kernel_launch(void* const* d_in, const int* in_sizes, int n_in,
                              void* d_out, int out_size, void* d_ws, size_t ws_size,
                              hipStream_t stream) {
    const float* inputs = (const float*)d_in[0];
    const float* W_ih1  = (const float*)d_in[1];
    const float* W_hh1  = (const float*)d_in[2];
    const float* b_ih1  = (const float*)d_in[3];
    const float* b_hh1  = (const float*)d_in[4];
    const float* W_ih2  = (const float*)d_in[5];
    const float* W_hh2  = (const float*)d_in[6];
    const float* b_ih2  = (const float*)d_in[7];
    const float* b_hh2  = (const float*)d_in[8];
    const float* W_halt = (const float*)d_in[9];
    const float* b_halt = (const float*)d_in[10];

    float* out = (float*)d_out;
    float* Z1  = out + O_H1;                  // 64 MB in d_out's dead state region

    char* wsb = (char*)d_ws;
    float* c1s = (float*)(wsb + WS_C1);
    float* c2s = (float*)(wsb + WS_C2);
    f16* h1hi = (f16*)(wsb + WS_H1HI);
    f16* h1lo = (f16*)(wsb + WS_H1LO);
    f16* h2hi = (f16*)(wsb + WS_H2HI);
    f16* h2lo = (f16*)(wsb + WS_H2LO);
    f16* acthi = (f16*)(wsb + WS_ACTHI);
    f16* actlo = (f16*)(wsb + WS_ACTLO);
    f16* W2hi = (f16*)(wsb + WS_W2HI);
    f16* W2lo = (f16*)(wsb + WS_W2LO);
    f16* W3hi = (f16*)(wsb + WS_W3HI);
    f16* W3lo = (f16*)(wsb + WS_W3LO);
    float* halt    = (float*)(wsb + WS_MISC);
    float* cont    = halt + 4096;
    float* flagcol = cont + 4096;
    unsigned* ctrl = (unsigned*)(flagcol + 4096);

    const bool packA = (ws_size >= WS_NEED_PACKA);
    f16* W4hi = (f16*)(wsb + WS_W4HI);
    f16* W4lo = (f16*)(wsb + WS_W4LO);

    // z1 temporaries in step-0-dead state slots: x pairs in h1, W1 pairs in h2
    f16* xhi  = h1hi; f16* xlo  = h1lo;
    f16* W1hi = h2hi; f16* W1lo = h2lo;

    k_small_init<<<16, 256, 0, stream>>>(halt, cont, out + O_PSTEP, ctrl);

    k_flagcol<<<16, 256, 0, stream>>>(W_ih1, flagcol);
    k_pack_w<<<2048, 256, 0, stream>>>(W_ih1, W1hi, W1lo, 1025);
    k_pack_w<<<2048, 256, 0, stream>>>(W_ih2, W2hi, W2lo, 1024);
    k_pack_w<<<2048, 256, 0, stream>>>(W_hh2, W3hi, W3lo, 1024);
    if (packA)
        k_pack_w<<<2048, 256, 0, stream>>>(W_hh1, W4hi, W4lo, 1024);
    k_split_flat<<<4096, 256, 0, stream>>>(inputs, xhi, xlo);
    k_z1<<<256, 512, 0, stream>>>(xhi, xlo, W1hi, W1lo, b_ih1, b_hh1, Z1);

    for (int s = 0; s < TSTEPS; ++s) {
        const unsigned* cnt_prev = ctrl + (s > 0 ? s - 1 : 0);

        if (packA)
            k_stepA<true><<<256, 512, 0, stream>>>(Z1, W_hh1, W4hi, W4lo,
                                                   flagcol, c1s,
                                                   h1hi, h1lo, acthi, actlo,
                                                   cnt_prev, s);
        else
            k_stepA<false><<<256, 512, 0, stream>>>(Z1, W_hh1, W4hi, W4lo,
                                                    flagcol, c1s,
                                                    h1hi, h1lo, acthi, actlo,
                                                    cnt_prev, s);
        k_stepB<<<256, 512, 0, stream>>>(acthi, actlo, W2hi, W2lo,
                                         h2hi, h2lo, W3hi, W3lo,
                                         b_ih2, b_hh2, c2s,
                                         cnt_prev, s);
        k_haltacc<<<1024, 256, 0, stream>>>(h2hi, h2lo, W_halt, b_halt,
                                            halt, cont, out + O_PSTEP, ctrl,
                                            out + O_ACC, cnt_prev, s);
    }

    k_fin1<<<4096, 256, 0, stream>>>(h1hi, h1lo, h2hi, h2lo,
                                     c1s, c2s, halt, cont, out);
    k_fin2<<<1, 256, 0, stream>>>(halt, out);
}

// Round 13
// 1332.629 us; speedup vs baseline: 1.4104x; 1.0273x over previous
//
#include <hip/hip_runtime.h>
#include <cstdint>
#include <cstddef>

// ---------------------------------------------------------------------------
// AdaptiveLSTMBlockWrapper — round 13: R10 occupancy shape + R11 packed
// weights combined. Tile 128x256, grid 512, 8 waves (2Mx4N), per-wave 64x64
// (acc 64 AGPR, VGPR ~64 -> 4 waves/SIMD, 2 independent blocks/CU).
// LDS 2x32KB A-only double buffer (proven 0-conflict geometry: 128B rows,
// 8x16B slots, slot^(row&7)). B = fragment-PACKED f16 hi/lo pairs loaded
// per-2-nf as single coalesced 1KB transactions; load latency covered by
// TLP (sibling block at independent phase), not software pipelining.
// fp32 GEMM = 3-product split-f16 MFMA (Ah*Bh + Ah*Bl + Al*Bh).
// ---------------------------------------------------------------------------

typedef _Float16 f16;
typedef f16   f16x8 __attribute__((ext_vector_type(8)));
typedef f16   f16x4 __attribute__((ext_vector_type(4)));
typedef float f32x4 __attribute__((ext_vector_type(4)));

#define TSTEPS 12

// d_out float offsets
#define O_ACC   0u
#define O_H1    4194304u
#define O_C1    8388608u
#define O_H2    12582912u
#define O_C2    16777216u
#define O_PCOST 20971520u
#define O_PSTEP 20971521u

// ws byte offsets
#define WS_C1    ((size_t)0u)
#define WS_C2    ((size_t)16u<<20)
#define WS_H1HI  ((size_t)32u<<20)
#define WS_H1LO  ((size_t)40u<<20)
#define WS_H2HI  ((size_t)48u<<20)
#define WS_H2LO  ((size_t)56u<<20)
#define WS_ACTHI ((size_t)64u<<20)
#define WS_ACTLO ((size_t)72u<<20)
#define WS_W2HI  ((size_t)80u<<20)
#define WS_W2LO  ((size_t)88u<<20)
#define WS_W3HI  ((size_t)96u<<20)
#define WS_W3LO  ((size_t)104u<<20)
#define WS_MISC  ((size_t)112u<<20)
// optional (only if ws_size >= WS_NEED_PACKA): packed Whh1 pairs
#define WS_W4HI  ((size_t)113u<<20)
#define WS_W4LO  ((size_t)121u<<20)
#define WS_NEED_PACKA ((size_t)129u<<20)

// LDS: 2 buffers; within a buffer: Ahi at 0 (16KB), Alo at 16384 (16KB)
#define SEC_ALO 16384
#define BUFSZ   32768

__device__ __forceinline__ float sigmoidf_(float x) { return 1.0f / (1.0f + expf(-x)); }

__device__ __forceinline__ void glds16(const void* g, void* l) {
    __builtin_amdgcn_global_load_lds(
        (const __attribute__((address_space(1))) unsigned int*)g,
        (__attribute__((address_space(3))) unsigned int*)l, 16, 0, 0);
}

// Grid: 512 blocks (32 m x 16 hc). XCD-major over hc: 2MB weight slab/XCD.
__device__ __forceinline__ void block_tile(int& m0, int& hc0) {
    const int bid = blockIdx.x;
    const int lid = (bid & 7) * 64 + (bid >> 3);
    m0  = (lid & 31) * 128;
    hc0 = (lid >> 5) * 64;
}

// ---------------------------------------------------------------------------
// acc += A(128 rows x 1024) * B(256 vcols x 1024)^T, split-f16 3-product.
// A: pre-split f16 pairs, glds into LDS (128B rows, 8x16B slots, invariant:
//    slot s of row r holds k-chunk s^(r&7)) — proven zero-conflict.
// B_PAIR: fragment-packed hi/lo pairs; per-(ks,np) load of 2 nf fragments =
//    2x2 coalesced 1KB transactions (base + C*1024 + lane*16).
//    chunk C = (hc0>>6)*512 + kt*32 + ks*16 + wnb*4 + nf.
// !B_PAIR: fp32 row-major gather + split on the fly (fallback only).
// Wave wid: rows wm=(wid>>2)*64 (mf 0..3), vcols nf group wnb=wid&3.
// ---------------------------------------------------------------------------
template<bool B_PAIR>
__device__ __forceinline__ void passK64(
    const f16* __restrict__ Ahi, const f16* __restrict__ Alo,
    const f16* __restrict__ Bhi, const f16* __restrict__ Blo,
    const float* __restrict__ Bf32,
    int m0, int hc0, f32x4 (&acc)[4][4], char* sm)
{
    const int tid = threadIdx.x, lane = tid & 63, wid = tid >> 6;
    const int wm  = (wid >> 2) * 64;
    const int wnb = wid & 3;
    const int l15 = lane & 15, lk = lane >> 4;

    // A fragment read offsets (per mf)
    int rbase[4], rx[4];
#pragma unroll
    for (int mf = 0; mf < 4; ++mf) {
        const int row = wm + mf * 16 + l15;
        rbase[mf] = row * 128;
        rx[mf]    = row & 7;
    }

    // A glds: 4 ops/wave. o = wid*4+i: sec = wid>>2, j = (wid&3)*4 + i.
    const int secA = wid >> 2;
    const int j0   = (wid & 3) * 4;
    const int rl = lane >> 3, sl = lane & 7;
    const f16* gaBase = (secA ? Alo : Ahi)
                        + (size_t)(m0 + j0 * 8 + rl) * 1024 + ((sl ^ rl) << 3);
    const int lb0 = secA * SEC_ALO + j0 * 1024;

    // B base pointers
    const float* pB32 = nullptr;
    const f16* pwh = nullptr;
    const f16* pwl = nullptr;
    if constexpr (B_PAIR) {
        const size_t pbase = ((size_t)((hc0 >> 6) * 512 + wnb * 4)) * 512 + (size_t)lane * 8;
        pwh = Bhi + pbase;
        pwl = Blo + pbase;
    } else {
        const int wrow0 = hc0 + wnb * 16 + l15;
        pB32 = Bf32 + (size_t)wrow0 * 1024 + lk * 8;
    }

    auto issueA = [&](int kt, char* buf) {
#pragma unroll
        for (int i = 0; i < 4; ++i)
            glds16(gaBase + (size_t)i * 8192 + kt * 64, buf + lb0 + i * 1024);
    };

    // ---- prologue ----
    issueA(0, sm);
    asm volatile("s_waitcnt vmcnt(0)" ::: "memory");
    __builtin_amdgcn_s_barrier();
    asm volatile("" ::: "memory");

#pragma unroll 1
    for (int kt = 0; kt < 16; ++kt) {
        char* bc = sm + (kt & 1) * BUFSZ;
        char* bn = sm + ((kt + 1) & 1) * BUFSZ;
        if (kt < 15) issueA(kt + 1, bn);

#pragma unroll
        for (int ks = 0; ks < 2; ++ks) {
#pragma unroll
            for (int np = 0; np < 2; ++np) {
                // load B fragments for nf = 2np, 2np+1
                f16x8 bh[2], bl[2];
#pragma unroll
                for (int q = 0; q < 2; ++q) {
                    if constexpr (B_PAIR) {
                        const size_t bo = (size_t)kt * 16384 + (size_t)ks * 8192
                                        + (size_t)(2 * np + q) * 512;
                        bh[q] = *(const f16x8*)(pwh + bo);
                        bl[q] = *(const f16x8*)(pwl + bo);
                    } else {
                        const size_t bo = (size_t)(2 * np + q) * 1048576 + kt * 64 + ks * 32;
                        const float* p = pB32 + bo;
                        const float4 v0 = *(const float4*)(p);
                        const float4 v1 = *(const float4*)(p + 4);
                        const float f[8] = {v0.x, v0.y, v0.z, v0.w, v1.x, v1.y, v1.z, v1.w};
                        f16x8 h, l;
#pragma unroll
                        for (int j = 0; j < 8; ++j) {
                            const f16 a = (f16)f[j];
                            h[j] = a; l[j] = (f16)(f[j] - (float)a);
                        }
                        bh[q] = h; bl[q] = l;
                    }
                }
#pragma unroll
                for (int mg = 0; mg < 2; ++mg) {
                    const int o0 = rbase[2 * mg]     + ((((ks << 2) | lk) ^ rx[2 * mg])     << 4);
                    const int o1 = rbase[2 * mg + 1] + ((((ks << 2) | lk) ^ rx[2 * mg + 1]) << 4);
                    const f16x8 ah0 = *(const f16x8*)(bc + o0);
                    const f16x8 al0 = *(const f16x8*)(bc + SEC_ALO + o0);
                    const f16x8 ah1 = *(const f16x8*)(bc + o1);
                    const f16x8 al1 = *(const f16x8*)(bc + SEC_ALO + o1);
                    __builtin_amdgcn_s_setprio(1);
#pragma unroll
                    for (int q = 0; q < 2; ++q) {
                        acc[2 * mg][2 * np + q]     = __builtin_amdgcn_mfma_f32_16x16x32_f16(ah0, bh[q], acc[2 * mg][2 * np + q], 0, 0, 0);
                        acc[2 * mg + 1][2 * np + q] = __builtin_amdgcn_mfma_f32_16x16x32_f16(ah1, bh[q], acc[2 * mg + 1][2 * np + q], 0, 0, 0);
                    }
#pragma unroll
                    for (int q = 0; q < 2; ++q) {
                        acc[2 * mg][2 * np + q]     = __builtin_amdgcn_mfma_f32_16x16x32_f16(ah0, bl[q], acc[2 * mg][2 * np + q], 0, 0, 0);
                        acc[2 * mg + 1][2 * np + q] = __builtin_amdgcn_mfma_f32_16x16x32_f16(ah1, bl[q], acc[2 * mg + 1][2 * np + q], 0, 0, 0);
                    }
#pragma unroll
                    for (int q = 0; q < 2; ++q) {
                        acc[2 * mg][2 * np + q]     = __builtin_amdgcn_mfma_f32_16x16x32_f16(al0, bh[q], acc[2 * mg][2 * np + q], 0, 0, 0);
                        acc[2 * mg + 1][2 * np + q] = __builtin_amdgcn_mfma_f32_16x16x32_f16(al1, bh[q], acc[2 * mg + 1][2 * np + q], 0, 0, 0);
                    }
                    __builtin_amdgcn_s_setprio(0);
                }
            }
        }
        asm volatile("s_waitcnt vmcnt(0)" ::: "memory");  // glds ~1 kt old
        if (kt < 15) {
            __builtin_amdgcn_s_barrier();
            asm volatile("" ::: "memory");
        }
    }
}

// Z1 = x@W1^T + b_ih1 + b_hh1 (x pairs staged; W1 packed pairs direct-to-reg)
__global__ __launch_bounds__(512, 4) void k_z1(
    const f16* __restrict__ xhi, const f16* __restrict__ xlo,
    const f16* __restrict__ W1hi, const f16* __restrict__ W1lo,
    const float* __restrict__ bih1, const float* __restrict__ bhh1,
    float* __restrict__ Z1)
{
    __shared__ __align__(16) char sm[2 * BUFSZ];
    int m0, hc0; block_tile(m0, hc0);
    f32x4 acc[4][4];
#pragma unroll
    for (int a = 0; a < 4; ++a)
#pragma unroll
        for (int b = 0; b < 4; ++b) acc[a][b] = (f32x4){0.f, 0.f, 0.f, 0.f};
    passK64<true>(xhi, xlo, W1hi, W1lo, nullptr, m0, hc0, acc, sm);

    const int tid = threadIdx.x, lane = tid & 63, wid = tid >> 6;
    const int wm = (wid >> 2) * 64, wnb = wid & 3, l15 = lane & 15, lk = lane >> 4;
    const int hc = hc0 + wnb * 16 + l15;
#pragma unroll
    for (int mf = 0; mf < 4; ++mf)
#pragma unroll
        for (int r = 0; r < 4; ++r) {
            const int row = m0 + wm + mf * 16 + lk * 4 + r;
#pragma unroll
            for (int g = 0; g < 4; ++g) {
                const int R = g * 1024 + hc;
                Z1[(size_t)row * 4096 + R] = acc[mf][g][r] + bih1[R] + bhh1[R];
            }
        }
}

// Layer-1 cell: gates = Z1 (+flag col @step0) + h1@Whh1^T  (in-place h1/act)
template<bool PACKED>
__global__ __launch_bounds__(512, 4) void k_stepA(
    const float* __restrict__ Z1, const float* __restrict__ Whh1,
    const f16* __restrict__ W4hi, const f16* __restrict__ W4lo,
    const float* __restrict__ flagcol, float* __restrict__ c1,
    f16* __restrict__ h1hi, f16* __restrict__ h1lo,
    f16* __restrict__ acthi, f16* __restrict__ actlo,
    const unsigned* __restrict__ cnt_prev, int step)
{
    if (step > 0 && cnt_prev[0] == 0u) return;
    __shared__ __align__(16) char sm[2 * BUFSZ];
    int m0, hc0; block_tile(m0, hc0);
    f32x4 acc[4][4];
#pragma unroll
    for (int a = 0; a < 4; ++a)
#pragma unroll
        for (int b = 0; b < 4; ++b) acc[a][b] = (f32x4){0.f, 0.f, 0.f, 0.f};
    if (step > 0) {
        if constexpr (PACKED)
            passK64<true>(h1hi, h1lo, W4hi, W4lo, nullptr, m0, hc0, acc, sm);
        else
            passK64<false>(h1hi, h1lo, nullptr, nullptr, Whh1, m0, hc0, acc, sm);
    }

    const int tid = threadIdx.x, lane = tid & 63, wid = tid >> 6;
    const int wm = (wid >> 2) * 64, wnb = wid & 3, l15 = lane & 15, lk = lane >> 4;
    const int hc = hc0 + wnb * 16 + l15;
#pragma unroll
    for (int mf = 0; mf < 4; ++mf)
#pragma unroll
        for (int r = 0; r < 4; ++r) {
            const int row = m0 + wm + mf * 16 + lk * 4 + r;
            float p[4];
#pragma unroll
            for (int g = 0; g < 4; ++g) {
                const int R = g * 1024 + hc;
                p[g] = acc[mf][g][r] + Z1[(size_t)row * 4096 + R];
                if (step == 0) p[g] += flagcol[R];
            }
            const float ig = sigmoidf_(p[0]);
            const float fg = sigmoidf_(p[1]);
            const float gg = tanhf(p[2]);
            const float og = sigmoidf_(p[3]);
            const int idx = row * 1024 + hc;
            const float cold = (step == 0) ? 0.0f : c1[idx];
            const float cn = fg * cold + ig * gg;
            c1[idx] = cn;
            const float h = og * tanhf(cn);
            const f16 hh = (f16)h;
            const f16 hl = (f16)(h - (float)hh);
            h1hi[idx] = hh; h1lo[idx] = hl;
            const bool pos = h > 0.0f;
            acthi[idx] = pos ? hh : (f16)0.0f;
            actlo[idx] = pos ? hl : (f16)0.0f;
        }
}

// Layer-2 cell: gates = b2 + act@Wih2^T + h2@Whh2^T (in-place h2; packed B)
__global__ __launch_bounds__(512, 4) void k_stepB(
    const f16* __restrict__ acthi, const f16* __restrict__ actlo,
    const f16* __restrict__ W2hi, const f16* __restrict__ W2lo,
    f16* __restrict__ h2hi, f16* __restrict__ h2lo,
    const f16* __restrict__ W3hi, const f16* __restrict__ W3lo,
    const float* __restrict__ bih2, const float* __restrict__ bhh2,
    float* __restrict__ c2,
    const unsigned* __restrict__ cnt_prev, int step)
{
    if (step > 0 && cnt_prev[0] == 0u) return;
    __shared__ __align__(16) char sm[2 * BUFSZ];
    int m0, hc0; block_tile(m0, hc0);
    f32x4 acc[4][4];
#pragma unroll
    for (int a = 0; a < 4; ++a)
#pragma unroll
        for (int b = 0; b < 4; ++b) acc[a][b] = (f32x4){0.f, 0.f, 0.f, 0.f};
    passK64<true>(acthi, actlo, W2hi, W2lo, nullptr, m0, hc0, acc, sm);
    if (step > 0)
        passK64<true>(h2hi, h2lo, W3hi, W3lo, nullptr, m0, hc0, acc, sm);

    const int tid = threadIdx.x, lane = tid & 63, wid = tid >> 6;
    const int wm = (wid >> 2) * 64, wnb = wid & 3, l15 = lane & 15, lk = lane >> 4;
    const int hc = hc0 + wnb * 16 + l15;
#pragma unroll
    for (int mf = 0; mf < 4; ++mf)
#pragma unroll
        for (int r = 0; r < 4; ++r) {
            const int row = m0 + wm + mf * 16 + lk * 4 + r;
            float p[4];
#pragma unroll
            for (int g = 0; g < 4; ++g) {
                const int R = g * 1024 + hc;
                p[g] = acc[mf][g][r] + bih2[R] + bhh2[R];
            }
            const float ig = sigmoidf_(p[0]);
            const float fg = sigmoidf_(p[1]);
            const float gg = tanhf(p[2]);
            const float og = sigmoidf_(p[3]);
            const int idx = row * 1024 + hc;
            const float cold = (step == 0) ? 0.0f : c2[idx];
            const float cn = fg * cold + ig * gg;
            c2[idx] = cn;
            const float h = og * tanhf(cn);
            const f16 hh = (f16)h;
            h2hi[idx] = hh;
            h2lo[idx] = (f16)(h - (float)hh);
        }
}

// Merged halting state machine + acc_out accumulate (one wave per row).
__global__ __launch_bounds__(256) void k_haltacc(
    const f16* __restrict__ h2hi, const f16* __restrict__ h2lo,
    const float* __restrict__ Whalt, const float* __restrict__ bhalt,
    float* __restrict__ halt, float* __restrict__ cont,
    float* __restrict__ ponder_out, unsigned* __restrict__ ctrl,
    float* __restrict__ acc_out,
    const unsigned* __restrict__ cnt_prev, int step)
{
    if (step > 0 && cnt_prev[0] == 0u) return;
    const int lane = threadIdx.x & 63;
    const int b = blockIdx.x * 4 + (threadIdx.x >> 6);
    const size_t base = (size_t)b * 1024;
    float sum = 0.0f;
    for (int k = lane; k < 1024; k += 64)
        sum += ((float)h2hi[base + k] + (float)h2lo[base + k]) * Whalt[k];
#pragma unroll
    for (int off = 32; off > 0; off >>= 1) sum += __shfl_down(sum, off, 64);
    float co = 0.0f;
    if (lane == 0) {
        const float sh = sigmoidf_(sum + bhalt[0]);
        if (cont[b] != 0.0f) {
            const float hn = halt[b] + sh;
            const bool ending = hn > 0.99f;
            co = sh + (ending ? (1.0f - hn) : 0.0f);
            halt[b] = hn;
            if (!ending) {
                ponder_out[b] += 1.0f;
                atomicAdd(&ctrl[step], 1u);
            } else {
                cont[b] = 0.0f;
            }
        }
    }
    co = __shfl(co, 0, 64);
    if (step == 0 || co != 0.0f) {
        float4* dst = (float4*)(acc_out + base);
        const f16x4* hi4 = (const f16x4*)(h2hi + base);
        const f16x4* lo4 = (const f16x4*)(h2lo + base);
#pragma unroll
        for (int j = 0; j < 4; ++j) {
            const int i = lane + 64 * j;
            const f16x4 hv = hi4[i];
            const f16x4 lv = lo4[i];
            float4 d = (step == 0) ? (float4){0.f, 0.f, 0.f, 0.f} : dst[i];
            d.x = fmaf(co, (float)hv[0] + (float)lv[0], d.x);
            d.y = fmaf(co, (float)hv[1] + (float)lv[1], d.y);
            d.z = fmaf(co, (float)hv[2] + (float)lv[2], d.z);
            d.w = fmaf(co, (float)hv[3] + (float)lv[3], d.w);
            dst[i] = d;
        }
    }
}

__global__ __launch_bounds__(256) void k_small_init(
    float* __restrict__ halt, float* __restrict__ cont,
    float* __restrict__ ponder_out, unsigned* __restrict__ ctrl)
{
    const int b = blockIdx.x * 256 + threadIdx.x;
    if (b < 4096) { halt[b] = 0.0f; cont[b] = 1.0f; ponder_out[b] = 0.0f; }
    if (b < 16) ctrl[b] = 0u;
}

// flat fp32 -> f16 hi/lo pairs, standard row-major (A-side: inputs x)
__global__ __launch_bounds__(256) void k_split_flat(
    const float* __restrict__ src, f16* __restrict__ hi, f16* __restrict__ lo)
{
    const size_t i = ((size_t)blockIdx.x * 256 + threadIdx.x) * 4;
    const float4 v = *(const float4*)(src + i);
    const f16 s0 = (f16)v.x, s1 = (f16)v.y, s2 = (f16)v.z, s3 = (f16)v.w;
    const f16x4 hv = {s0, s1, s2, s3};
    const f16x4 lw = {(f16)(v.x - (float)s0), (f16)(v.y - (float)s1),
                      (f16)(v.z - (float)s2), (f16)(v.w - (float)s3)};
    *(f16x4*)(hi + i) = hv;
    *(f16x4*)(lo + i) = lw;
}

// Weight -> fragment-PACKED f16 hi/lo pairs.
// t = C*64 + lane; C = T*512 + kt*32 + ks*16 + wnb*4 + nf.
// src row = nf*1024 + T*64 + wnb*16 + (lane&15); k0 = kt*64+ks*32+(lane>>4)*8.
__global__ __launch_bounds__(256) void k_pack_w(
    const float* __restrict__ src, f16* __restrict__ hi, f16* __restrict__ lo,
    int stride)
{
    const size_t t = (size_t)blockIdx.x * 256 + threadIdx.x;   // 524288 total
    const int lane = (int)(t & 63);
    const size_t C = t >> 6;
    const int nf  = (int)(C & 3);
    const int wnb = (int)((C >> 2) & 3);
    const int ks  = (int)((C >> 4) & 1);
    const int kt  = (int)((C >> 5) & 15);
    const int T   = (int)(C >> 9);
    const int row = nf * 1024 + T * 64 + wnb * 16 + (lane & 15);
    const int k0  = kt * 64 + ks * 32 + (lane >> 4) * 8;
    const float* s = src + (size_t)row * stride + k0;
    f16x8 h, l;
#pragma unroll
    for (int j = 0; j < 8; ++j) {
        const float v = s[j];
        const f16 a = (f16)v;
        h[j] = a; l[j] = (f16)(v - (float)a);
    }
    *(f16x8*)(hi + t * 8) = h;
    *(f16x8*)(lo + t * 8) = l;
}

// extract W_ih1 column 1024 (flag column)
__global__ __launch_bounds__(256) void k_flagcol(
    const float* __restrict__ Wih1, float* __restrict__ flagcol)
{
    const int r = blockIdx.x * 256 + threadIdx.x;
    if (r < 4096) flagcol[r] = Wih1[(size_t)r * 1025 + 1024];
}

// finalize: states to d_out + remainder term
__global__ __launch_bounds__(256) void k_fin1(
    const f16* __restrict__ h1hi, const f16* __restrict__ h1lo,
    const f16* __restrict__ h2hi, const f16* __restrict__ h2lo,
    const float* __restrict__ c1s, const float* __restrict__ c2s,
    const float* __restrict__ halt, const float* __restrict__ cont,
    float* __restrict__ out)
{
    const int b = blockIdx.x;
    const float rem = (cont[b] != 0.0f) ? (1.0f - halt[b]) : 0.0f;
    const int base = b * 1024;
    for (int i = threadIdx.x; i < 1024; i += 256) {
        const float h1v = (float)h1hi[base + i] + (float)h1lo[base + i];
        const float h2v = (float)h2hi[base + i] + (float)h2lo[base + i];
        out[O_H1 + base + i] = h1v;
        out[O_C1 + base + i] = c1s[base + i];
        out[O_H2 + base + i] = h2v;
        out[O_C2 + base + i] = c2s[base + i];
        if (rem != 0.0f) out[O_ACC + base + i] += rem * h2v;
    }
}

__global__ __launch_bounds__(256) void k_fin2(
    const float* __restrict__ halt, float* __restrict__ out)
{
    __shared__ float red[256];
    float s = 0.0f;
    for (int i = threadIdx.x; i < 4096; i += 256) s += halt[i];
    red[threadIdx.x] = s;
    __syncthreads();
    for (int w = 128; w > 0; w >>= 1) {
        if (threadIdx.x < w) red[threadIdx.x] += red[threadIdx.x + w];
        __syncthreads();
    }
    if (threadIdx.x == 0) out[O_PCOST] = -0.01f * (red[0] * (1.0f / 4096.0f));
}

extern "C" void kernel_launch(void* const* d_in, const int* in_sizes, int n_in,
                              void* d_out, int out_size, void* d_ws, size_t ws_size,
                              hipStream_t stream) {
    const float* inputs = (const float*)d_in[0];
    const float* W_ih1  = (const float*)d_in[1];
    const float* W_hh1  = (const float*)d_in[2];
    const float* b_ih1  = (const float*)d_in[3];
    const float* b_hh1  = (const float*)d_in[4];
    const float* W_ih2  = (const float*)d_in[5];
    const float* W_hh2  = (const float*)d_in[6];
    const float* b_ih2  = (const float*)d_in[7];
    const float* b_hh2  = (const float*)d_in[8];
    const float* W_halt = (const float*)d_in[9];
    const float* b_halt = (const float*)d_in[10];

    float* out = (float*)d_out;
    float* Z1  = out + O_H1;                  // 64 MB in d_out's dead state region

    char* wsb = (char*)d_ws;
    float* c1s = (float*)(wsb + WS_C1);
    float* c2s = (float*)(wsb + WS_C2);
    f16* h1hi = (f16*)(wsb + WS_H1HI);
    f16* h1lo = (f16*)(wsb + WS_H1LO);
    f16* h2hi = (f16*)(wsb + WS_H2HI);
    f16* h2lo = (f16*)(wsb + WS_H2LO);
    f16* acthi = (f16*)(wsb + WS_ACTHI);
    f16* actlo = (f16*)(wsb + WS_ACTLO);
    f16* W2hi = (f16*)(wsb + WS_W2HI);
    f16* W2lo = (f16*)(wsb + WS_W2LO);
    f16* W3hi = (f16*)(wsb + WS_W3HI);
    f16* W3lo = (f16*)(wsb + WS_W3LO);
    float* halt    = (float*)(wsb + WS_MISC);
    float* cont    = halt + 4096;
    float* flagcol = cont + 4096;
    unsigned* ctrl = (unsigned*)(flagcol + 4096);

    const bool packA = (ws_size >= WS_NEED_PACKA);
    f16* W4hi = (f16*)(wsb + WS_W4HI);
    f16* W4lo = (f16*)(wsb + WS_W4LO);

    // z1 temporaries in step-0-dead state slots: x pairs in h1, W1 pairs in h2
    f16* xhi  = h1hi; f16* xlo  = h1lo;
    f16* W1hi = h2hi; f16* W1lo = h2lo;

    k_small_init<<<16, 256, 0, stream>>>(halt, cont, out + O_PSTEP, ctrl);

    k_flagcol<<<16, 256, 0, stream>>>(W_ih1, flagcol);
    k_pack_w<<<2048, 256, 0, stream>>>(W_ih1, W1hi, W1lo, 1025);
    k_pack_w<<<2048, 256, 0, stream>>>(W_ih2, W2hi, W2lo, 1024);
    k_pack_w<<<2048, 256, 0, stream>>>(W_hh2, W3hi, W3lo, 1024);
    if (packA)
        k_pack_w<<<2048, 256, 0, stream>>>(W_hh1, W4hi, W4lo, 1024);
    k_split_flat<<<4096, 256, 0, stream>>>(inputs, xhi, xlo);
    k_z1<<<512, 512, 0, stream>>>(xhi, xlo, W1hi, W1lo, b_ih1, b_hh1, Z1);

    for (int s = 0; s < TSTEPS; ++s) {
        const unsigned* cnt_prev = ctrl + (s > 0 ? s - 1 : 0);

        if (packA)
            k_stepA<true><<<512, 512, 0, stream>>>(Z1, W_hh1, W4hi, W4lo,
                                                   flagcol, c1s,
                                                   h1hi, h1lo, acthi, actlo,
                                                   cnt_prev, s);
        else
            k_stepA<false><<<512, 512, 0, stream>>>(Z1, W_hh1, W4hi, W4lo,
                                                    flagcol, c1s,
                                                    h1hi, h1lo, acthi, actlo,
                                                    cnt_prev, s);
        k_stepB<<<512, 512, 0, stream>>>(acthi, actlo, W2hi, W2lo,
                                         h2hi, h2lo, W3hi, W3lo,
                                         b_ih2, b_hh2, c2s,
                                         cnt_prev, s);
        k_haltacc<<<1024, 256, 0, stream>>>(h2hi, h2lo, W_halt, b_halt,
                                            halt, cont, out + O_PSTEP, ctrl,
                                            out + O_ACC, cnt_prev, s);
    }

    k_fin1<<<4096, 256, 0, stream>>>(h1hi, h1lo, h2hi, h2lo,
                                     c1s, c2s, halt, cont, out);
    k_fin2<<<1, 256, 0, stream>>>(halt, out);
}